// Round 12
// baseline (238.619 us; speedup 1.0000x reference)
//
#include <hip/hip_runtime.h>

#define B_SZ   8
#define S_LEN  4096
#define D_K    128
#define KB     64      // keys per step
#define CH     8       // steps per chunk
// 128-q tiles (32/batch), tile q needs 2q+2 steps; chunks of <=8 steps:
// sum over q of ceil((2q+2)/8) = 144 per batch -> 1152 chunks total.
#define NCHUNK 1152
#define NC(q)  (((q) + 4) >> 2)   // ceil((q+1)/4) = chunks for tile q

typedef short  short8  __attribute__((ext_vector_type(8)));
typedef float  floatx4 __attribute__((ext_vector_type(4)));

// raw v_exp_f32 (2^x) where available; args are always <= 0 here (no range issues)
#if defined(__has_builtin)
#if __has_builtin(__builtin_amdgcn_exp2f)
#define EXP2F(x) __builtin_amdgcn_exp2f(x)
#endif
#endif
#ifndef EXP2F
#define EXP2F(x) exp2f(x)
#endif

__device__ __forceinline__ unsigned bfround(float x) {
  unsigned u = __builtin_bit_cast(unsigned, x);
  return (u + 0x7fffu + ((u >> 16) & 1u)) >> 16;
}
__device__ __forceinline__ unsigned bfpack2(float a, float b) {
  return bfround(a) | (bfround(b) << 16);
}
// single-instruction RTNE pack (hot loop only; numerics validated R1-R10)
__device__ __forceinline__ unsigned cvtpk(float lo, float hi) {
  unsigned r;
  asm("v_cvt_pk_bf16_f32 %0, %1, %2" : "=v"(r) : "v"(lo), "v"(hi));
  return r;
}

// NOTE (R6): permlane16/32_swap reductions failed correctness. __shfl_xor only.
// NOTE (R9): __launch_bounds__ 2nd arg acts as min BLOCKS/CU on this toolchain;
// (256,3) -> VGPR cap 170 under either semantic; working set ~104 fits.

// Async global->LDS DMA, 16B per lane (wave writes 1024B contiguous LDS).
__device__ __forceinline__ void dma16(const void* g, const void* l) {
  __builtin_amdgcn_global_load_lds(
      (__attribute__((address_space(1))) unsigned int*)(unsigned long long)g,
      (__attribute__((address_space(3))) unsigned int*)(unsigned int)(unsigned long long)l,
      16, 0, 0);
}

// ======================= pre-pass: tile-image builder (R3-R10 proven) =======================
// One block per (b, step s): K and V^T as 16KB tile IMAGES with the XOR
// bank-swizzle baked in (byte ^= ((row&7)<<4)); worker DMAs them linearly.
// Block 0 zeroes the chunk counter.

__global__ __launch_bounds__(256)
void prep(const float* __restrict__ K, const float* __restrict__ V,
          unsigned short* __restrict__ Kb, unsigned short* __restrict__ Vt,
          int* __restrict__ cnt) {
  __shared__ float tile[64][129];
  const int tid = threadIdx.x;
  const int bid = blockIdx.x;         // b*64 + s
  if (bid == 0 && tid == 0) *cnt = 0;
  const int b   = bid >> 6;
  const int s   = bid & 63;
  const int kt  = s * 64;

  // ---- K tile image ----
  {
    const int r  = tid >> 2;
    const int cq = tid & 3;
    const float* kp = K + (size_t)(b * S_LEN + kt + r) * D_K + cq * 32;
    unsigned short* kdst = Kb + (size_t)bid * 8192 + r * 128;
    const int xr = (r & 7) << 4;
#pragma unroll
    for (int jj = 0; jj < 4; ++jj) {
      float4 f0 = *(const float4*)(kp + jj * 8);
      float4 f1 = *(const float4*)(kp + jj * 8 + 4);
      uint4 u;
      u.x = bfpack2(f0.x, f0.y);
      u.y = bfpack2(f0.z, f0.w);
      u.z = bfpack2(f1.x, f1.y);
      u.w = bfpack2(f1.z, f1.w);
      const int o = (cq * 64 + jj * 16) ^ xr;
      *(uint4*)(kdst + (o >> 1)) = u;
    }
  }

  // ---- V tile: load to LDS f32 ----
  {
    const int k  = tid >> 2;
    const int cq = tid & 3;
    const float* vp = V + (size_t)(b * S_LEN + kt + k) * D_K + cq * 32;
#pragma unroll
    for (int i = 0; i < 8; ++i) {
      float4 f = *(const float4*)(vp + i * 4);
      tile[k][cq * 32 + i * 4]     = f.x;
      tile[k][cq * 32 + i * 4 + 1] = f.y;
      tile[k][cq * 32 + i * 4 + 2] = f.z;
      tile[k][cq * 32 + i * 4 + 3] = f.w;
    }
  }
  __syncthreads();

  // ---- V^T tile image (transposed + swizzled) ----
  {
    const int d = tid >> 1;
    const int h = tid & 1;
    unsigned short* vdst = Vt + (size_t)bid * 8192 + d * 64;
    const int xr = (d & 7) << 4;
#pragma unroll
    for (int jj = 0; jj < 4; ++jj) {
      const int k0 = h * 32 + jj * 8;
      uint4 u;
      u.x = bfpack2(tile[k0 + 0][d], tile[k0 + 1][d]);
      u.y = bfpack2(tile[k0 + 2][d], tile[k0 + 3][d]);
      u.z = bfpack2(tile[k0 + 4][d], tile[k0 + 5][d]);
      u.w = bfpack2(tile[k0 + 6][d], tile[k0 + 7][d]);
      const int o = (h * 64 + jj * 16) ^ xr;
      *(uint4*)(vdst + (o >> 1)) = u;
    }
  }
}

// ======================= worker kernel =======================
// R12 == R11 resubmit (infra flake; audit found no kernel-side kill path).
// R7 skeleton (4 waves, 128-q tile, atomic LPT stealing) with LDS cut to
// 49,152B -> 3 blocks/CU = 3 waves/SIMD (+50% TLP): K double-buffered (2x16KB),
// V SINGLE-buffered (16KB, staged one step ahead), P through the dead K buffer
// (R10-proven). Per-step wait order (2 barriers, race-checked):
//   QKT(s) -> vmcnt(0) -> barrier1   [K[cur] becomes P scratch; all waves'
//                                     V(s)/K(s+1) DMAs landed -> visible]
//   softmax + P roundtrip + PV(s) -> lgkmcnt(0) -> barrier2
//   STAGE K(s+2) -> K[cur], V(s+1) -> V     [no wait; next step's vmcnt covers]
// CH=8 chunks (1152) over grid 768 = single-generation stealing schedule.

__global__ __launch_bounds__(256, 3)
void attn_worker(const float* __restrict__ Q, const unsigned short* __restrict__ Kb,
                 const unsigned short* __restrict__ Vt, int* __restrict__ cnt,
                 float* __restrict__ ml, float* __restrict__ pO) {
  __shared__ __align__(16) short Klds[2][8192];   // 2 x 16KB (also P scratch)
  __shared__ __align__(16) short Vtlds[8192];     // 16KB single buffer
  __shared__ int s_chunk;

  const int tid  = threadIdx.x;
  const int lane = tid & 63;
  const int w    = tid >> 6;        // wave 0..3
  const int l15  = lane & 15;
  const int quad = lane >> 4;
  const int xk   = (l15 & 7) << 3;  // short-index XOR for swizzled LDS reads

  const float CSC = 0.12752041f;    // log2(e)/sqrt(128)

  for (;;) {
    if (tid == 0) s_chunk = atomicAdd(cnt, 1);
    __syncthreads();
    const int c = s_chunk;
    if (c >= NCHUNK) break;

    // ---- decode: b = c&7; tiles enumerated q=31 down (LPT) ----
    const int b = c & 7;
    int q = 31, r = c >> 3;           // r in [0,144)
    while (r >= NC(q)) { r -= NC(q); --q; }
    const int j  = r;
    const int q0 = q * 128;
    const int s0 = j * CH;
    const int s1 = min(s0 + CH, 2 * q + 2);

    // ---- Q fragments for 2 subtiles (B-operand: n=l15=query, k=quad*8+i=d) ----
    short8 bq[2][4];
    int qg[2];
#pragma unroll
    for (int sub = 0; sub < 2; ++sub) {
      qg[sub] = q0 + w * 32 + sub * 16 + l15;
      const float* qrow = Q + (size_t)(b * S_LEN + qg[sub]) * D_K + quad * 8;
#pragma unroll
      for (int kd = 0; kd < 4; ++kd) {
        float4 f0 = *(const float4*)(qrow + kd * 32);
        float4 f1 = *(const float4*)(qrow + kd * 32 + 4);
        union { short8 s; unsigned u[4]; } tt;
        tt.u[0] = bfpack2(f0.x, f0.y);
        tt.u[1] = bfpack2(f0.z, f0.w);
        tt.u[2] = bfpack2(f1.x, f1.y);
        tt.u[3] = bfpack2(f1.z, f1.w);
        bq[sub][kd] = tt.s;
      }
    }

    floatx4 acc[2][8];
#pragma unroll
    for (int sub = 0; sub < 2; ++sub)
#pragma unroll
      for (int nc = 0; nc < 8; ++nc) acc[sub][nc] = (floatx4){0.f, 0.f, 0.f, 0.f};
    float m_run[2] = {-1e30f, -1e30f}, l_run[2] = {0.f, 0.f};

    const unsigned short* kb0 = Kb + (size_t)b * 64 * 8192;   // tile images
    const unsigned short* vb0 = Vt + (size_t)b * 64 * 8192;
    const int lo = lane * 8;            // lane*16B in shorts

    // each wave stages its quarter (4KB) of a 16KB tile = 4 dma16
#define STAGE_K(BUF, S)                                                        \
    do {                                                                       \
      const unsigned short* kg_ = kb0 + (size_t)(S) * 8192 + w * 2048 + lo;    \
      short* kl_ = &Klds[BUF][w * 2048];                                       \
      _Pragma("unroll")                                                        \
      for (int i_ = 0; i_ < 4; ++i_) dma16(kg_ + i_ * 512, kl_ + i_ * 512);    \
    } while (0)
#define STAGE_V(S)                                                             \
    do {                                                                       \
      const unsigned short* vg_ = vb0 + (size_t)(S) * 8192 + w * 2048 + lo;    \
      short* vl_ = &Vtlds[w * 2048];                                           \
      _Pragma("unroll")                                                        \
      for (int i_ = 0; i_ < 4; ++i_) dma16(vg_ + i_ * 512, vl_ + i_ * 512);    \
    } while (0)

    // ---- prologue: K(s0), K(s0+1), V(s0); wait all, barrier ----
    STAGE_K(s0 & 1, s0);
    if (s0 + 1 < s1) STAGE_K((s0 + 1) & 1, s0 + 1);
    STAGE_V(s0);
    asm volatile("s_waitcnt vmcnt(0)" ::: "memory");
    __builtin_amdgcn_s_barrier();
    __builtin_amdgcn_sched_barrier(0);

    for (int s = s0; s < s1; ++s) {
      const int kt  = s * KB;
      const int cur = s & 1;
      const short* Kl = &Klds[cur][0];
      const bool act = (kt <= q0 + w * 32 + 31);   // wave fully masked beyond

      floatx4 st[2][4];
      if (act) {
        // ---- S^T = K*Q^T for both subtiles; each A-frag read used twice ----
        __builtin_amdgcn_s_setprio(1);
#pragma unroll
        for (int kf = 0; kf < 4; ++kf) {
          floatx4 c0 = (floatx4){0.f, 0.f, 0.f, 0.f};
          floatx4 c1 = (floatx4){0.f, 0.f, 0.f, 0.f};
#pragma unroll
          for (int kd = 0; kd < 4; ++kd) {
            short8 a = *(const short8*)(&Kl[((kf * 16 + l15) << 7) + ((kd * 32 + quad * 8) ^ xk)]);
            c0 = __builtin_amdgcn_mfma_f32_16x16x32_bf16(a, bq[0][kd], c0, 0, 0, 0);
            c1 = __builtin_amdgcn_mfma_f32_16x16x32_bf16(a, bq[1][kd], c1, 0, 0, 0);
          }
          st[0][kf] = c0;
          st[1][kf] = c1;
        }
        __builtin_amdgcn_s_setprio(0);

        // ---- causal mask (boundary subtiles only) ----
#pragma unroll
        for (int sub = 0; sub < 2; ++sub) {
          if (kt + 63 > q0 + w * 32 + sub * 16) {
#pragma unroll
            for (int kf = 0; kf < 4; ++kf)
#pragma unroll
              for (int rr = 0; rr < 4; ++rr) {
                int key = kt + kf * 16 + quad * 4 + rr;
                if (key > qg[sub]) st[sub][kf][rr] = -1e30f;
              }
          }
        }
      }

      // own DMAs (V(s), K(s+1)) done; barrier => ALL waves' DMAs visible AND
      // K[cur] fully consumed block-wide (becomes P scratch).
      asm volatile("s_waitcnt vmcnt(0)" ::: "memory");
      __builtin_amdgcn_s_barrier();
      __builtin_amdgcn_sched_barrier(0);

      short8 pa[2][2];
      if (act) {
        // ---- online softmax + P roundtrip (through Klds[cur]) per subtile ----
        short* pw = &Klds[cur][(w * 16 + l15) << 6];   // wave-private 64-short row
#pragma unroll
        for (int sub = 0; sub < 2; ++sub) {
          float mx = st[sub][0][0];
#pragma unroll
          for (int kf = 0; kf < 4; ++kf)
#pragma unroll
            for (int rr = 0; rr < 4; ++rr) mx = fmaxf(mx, st[sub][kf][rr]);
          mx = fmaxf(mx, __shfl_xor(mx, 16, 64));
          mx = fmaxf(mx, __shfl_xor(mx, 32, 64));
          const float m_new = fmaxf(m_run[sub], mx);
          const bool  grow  = __any(m_new > m_run[sub]);

          float p[4][4];
          float tsum = 0.f;
#pragma unroll
          for (int kf = 0; kf < 4; ++kf)
#pragma unroll
            for (int rr = 0; rr < 4; ++rr) {
              p[kf][rr] = EXP2F((st[sub][kf][rr] - m_new) * CSC);
              tsum += p[kf][rr];
            }
          tsum += __shfl_xor(tsum, 16, 64);
          tsum += __shfl_xor(tsum, 32, 64);

          if (grow) {
            const float alpha = EXP2F((m_run[sub] - m_new) * CSC);
            l_run[sub] = l_run[sub] * alpha + tsum;
#pragma unroll
            for (int rr = 0; rr < 4; ++rr) {
              const float ar = __shfl(alpha, quad * 4 + rr, 64);
#pragma unroll
              for (int nc = 0; nc < 8; ++nc) acc[sub][nc][rr] *= ar;
            }
          } else {
            l_run[sub] = l_run[sub] + tsum;   // m_new == m_run for every query
          }
          m_run[sub] = m_new;

          // P: C-layout -> A-layout; XOR-swizzled stride-64 rows (in-order per wave)
#pragma unroll
          for (int kf = 0; kf < 4; ++kf) {
            uint2 u;
            u.x = cvtpk(p[kf][0], p[kf][1]);
            u.y = cvtpk(p[kf][2], p[kf][3]);
            *(uint2*)(&pw[(kf * 16 + quad * 4) ^ xk]) = u;
          }
          __asm__ __volatile__("" ::: "memory");
          pa[sub][0] = *(const short8*)(&pw[(quad * 8) ^ xk]);
          pa[sub][1] = *(const short8*)(&pw[(32 + quad * 8) ^ xk]);
          __asm__ __volatile__("" ::: "memory");
        }

        // ---- O += P*V ; each B-frag read used by both subtiles ----
        __builtin_amdgcn_s_setprio(1);
#pragma unroll
        for (int nc = 0; nc < 8; ++nc) {
          short8 bv0 = *(const short8*)(&Vtlds[((nc * 16 + l15) << 6) + ((quad * 8) ^ xk)]);
          short8 bv1 = *(const short8*)(&Vtlds[((nc * 16 + l15) << 6) + ((32 + quad * 8) ^ xk)]);
          acc[0][nc] = __builtin_amdgcn_mfma_f32_16x16x32_bf16(pa[0][0], bv0, acc[0][nc], 0, 0, 0);
          acc[0][nc] = __builtin_amdgcn_mfma_f32_16x16x32_bf16(pa[0][1], bv1, acc[0][nc], 0, 0, 0);
          acc[1][nc] = __builtin_amdgcn_mfma_f32_16x16x32_bf16(pa[1][0], bv0, acc[1][nc], 0, 0, 0);
          acc[1][nc] = __builtin_amdgcn_mfma_f32_16x16x32_bf16(pa[1][1], bv1, acc[1][nc], 0, 0, 0);
        }
        __builtin_amdgcn_s_setprio(0);
      }

      // ---- all P-scratch & V reads done -> stage next ----
      asm volatile("s_waitcnt lgkmcnt(0)" ::: "memory");
      __builtin_amdgcn_s_barrier();
      __builtin_amdgcn_sched_barrier(0);
      if (s + 2 < s1) STAGE_K(cur, s + 2);
      if (s + 1 < s1) STAGE_V(s + 1);
      // no wait here: next step's vmcnt(0) (after QKT) covers these
    }
#undef STAGE_K
#undef STAGE_V

    // ---- partial epilogue: unnormalized O + (m,l); slot == c ----
    float* po = pO + (size_t)c * 16384;
#pragma unroll
    for (int sub = 0; sub < 2; ++sub) {
#pragma unroll
      for (int rr = 0; rr < 4; ++rr) {
        const int qrow = w * 32 + sub * 16 + quad * 4 + rr;
        float* op = po + qrow * D_K + l15;
#pragma unroll
        for (int nc = 0; nc < 8; ++nc) op[nc * 16] = acc[sub][nc][rr];
      }
      if (quad == 0) {
        const int qrow = w * 32 + sub * 16 + l15;
        ml[(size_t)c * 256 + qrow * 2]     = m_run[sub];
        ml[(size_t)c * 256 + qrow * 2 + 1] = l_run[sub];
      }
    }
  }
}

// ======================= combine kernel =======================
// 256 blocks = b*32 + q (128-q tiles); up to 8 partials per tile.

__global__ __launch_bounds__(256)
void attn_combine(const float* __restrict__ ml, const float* __restrict__ pO,
                  float* __restrict__ O) {
  const int t = blockIdx.x;           // 0..255 = b*32 + q
  const int b = t >> 5;
  const int q = t & 31;
  const float CSC = 0.12752041f;

  const int tid = threadIdx.x;
  const int ql  = tid >> 1;           // 0..127
  const int dh  = (tid & 1) * 64;     // d-span of 64 floats

  int cum = 0;
  for (int tq = 31; tq > q; --tq) cum += NC(tq);
  const int ncb = NC(q);              // 1..8

  float m[8], l[8], wgt[8];
  float M = -1e30f;
#pragma unroll
  for (int i = 0; i < 8; ++i) {
    if (i < ncb) {
      const size_t slot = (size_t)((cum + i) << 3 | b);
      m[i] = ml[slot * 256 + ql * 2];
      l[i] = ml[slot * 256 + ql * 2 + 1];
      M = fmaxf(M, m[i]);
    }
  }
  float L = 0.f;
#pragma unroll
  for (int i = 0; i < 8; ++i)
    if (i < ncb) { wgt[i] = EXP2F((m[i] - M) * CSC); L += wgt[i] * l[i]; }
  const float inv = 1.0f / L;

  float4 out[16];
#pragma unroll
  for (int v = 0; v < 16; ++v) out[v] = make_float4(0.f, 0.f, 0.f, 0.f);
#pragma unroll
  for (int i = 0; i < 8; ++i) {
    if (i < ncb) {
      const size_t slot = (size_t)((cum + i) << 3 | b);
      const float* src = pO + slot * 16384 + ql * D_K + dh;
      const float wj = wgt[i];
#pragma unroll
      for (int v = 0; v < 16; ++v) {
        float4 f = *(const float4*)(src + v * 4);
        out[v].x += wj * f.x;  out[v].y += wj * f.y;
        out[v].z += wj * f.z;  out[v].w += wj * f.w;
      }
    }
  }
  float* dst = O + ((size_t)(b * S_LEN) + q * 128 + ql) * D_K + dh;
#pragma unroll
  for (int v = 0; v < 16; ++v) {
    *(float4*)(dst + v * 4) = make_float4(out[v].x * inv, out[v].y * inv,
                                          out[v].z * inv, out[v].w * inv);
  }
}

// ======================= fallback (known-good, ws-too-small path) =======================

#define KT_STR 136
#define VT_STR 72
#define PT_STR 72

__global__ __launch_bounds__(256, 2)
void attn_fwd_fb(const float* __restrict__ Q, const float* __restrict__ K,
                 const float* __restrict__ V, float* __restrict__ O) {
  __shared__ __align__(16) short Klds[KB * KT_STR];
  __shared__ __align__(16) short Vtlds[D_K * VT_STR];
  __shared__ __align__(16) short Plds[4 * 16 * PT_STR];

  const int tid  = threadIdx.x;
  const int lane = tid & 63;
  const int w    = tid >> 6;
  const int l15  = lane & 15;
  const int quad = lane >> 4;

  const int bid = blockIdx.x;
  const int b   = bid & 7;
  const int qi  = 63 - (bid >> 3);
  const int q0  = qi * 64;

  const float CSC = 0.12752041f;

  const int    qg   = q0 + w * 16 + l15;
  const float* qrow = Q + (size_t)(b * S_LEN + qg) * D_K + quad * 8;
  short8 bq[4];
#pragma unroll
  for (int kd = 0; kd < 4; ++kd) {
    float4 f0 = *(const float4*)(qrow + kd * 32);
    float4 f1 = *(const float4*)(qrow + kd * 32 + 4);
    union { short8 s; unsigned u[4]; } t;
    t.u[0] = bfpack2(f0.x, f0.y);
    t.u[1] = bfpack2(f0.z, f0.w);
    t.u[2] = bfpack2(f1.x, f1.y);
    t.u[3] = bfpack2(f1.z, f1.w);
    bq[kd] = t.s;
  }

  floatx4 acc[8];
#pragma unroll
  for (int nc = 0; nc < 8; ++nc) acc[nc] = (floatx4){0.f, 0.f, 0.f, 0.f};
  float m_run = -1e30f, l_run = 0.f;

  const int d4 = tid & 31;
  const int kq = tid >> 5;
  const int nsteps = qi + 1;

  for (int s = 0; s < nsteps; ++s) {
    const int kt = s * KB;
#pragma unroll
    for (int r2 = 0; r2 < 2; ++r2) {
      const int row = r2 * 32 + kq * 4;
      const float* kp = K + (size_t)(b * S_LEN + kt + row) * D_K + d4 * 4;
      const float* vp = V + (size_t)(b * S_LEN + kt + row) * D_K + d4 * 4;
      float4 fk[4], fv[4];
#pragma unroll
      for (int i = 0; i < 4; ++i) {
        fk[i] = *(const float4*)(kp + i * D_K);
        fv[i] = *(const float4*)(vp + i * D_K);
      }
#pragma unroll
      for (int i = 0; i < 4; ++i) {
        uint2 u;
        u.x = bfpack2(fk[i].x, fk[i].y);
        u.y = bfpack2(fk[i].z, fk[i].w);
        *(uint2*)(&Klds[(row + i) * KT_STR + d4 * 4]) = u;
      }
#pragma unroll
      for (int c = 0; c < 4; ++c) {
        float e0 = ((const float*)&fv[0])[c];
        float e1 = ((const float*)&fv[1])[c];
        float e2 = ((const float*)&fv[2])[c];
        float e3 = ((const float*)&fv[3])[c];
        uint2 u;
        u.x = bfpack2(e0, e1);
        u.y = bfpack2(e2, e3);
        *(uint2*)(&Vtlds[(d4 * 4 + c) * VT_STR + row]) = u;
      }
    }
    __syncthreads();

    floatx4 st[4];
#pragma unroll
    for (int kf = 0; kf < 4; ++kf) {
      floatx4 cc = (floatx4){0.f, 0.f, 0.f, 0.f};
#pragma unroll
      for (int kd = 0; kd < 4; ++kd) {
        short8 a = *(const short8*)(&Klds[(kf * 16 + l15) * KT_STR + kd * 32 + quad * 8]);
        cc = __builtin_amdgcn_mfma_f32_16x16x32_bf16(a, bq[kd], cc, 0, 0, 0);
      }
      st[kf] = cc;
    }

    if (s == nsteps - 1) {
#pragma unroll
      for (int kf = 0; kf < 4; ++kf)
#pragma unroll
        for (int rr = 0; rr < 4; ++rr) {
          int key = kt + kf * 16 + quad * 4 + rr;
          if (key > qg) st[kf][rr] = -1e30f;
        }
    }

    float mx = st[0][0];
#pragma unroll
    for (int kf = 0; kf < 4; ++kf)
#pragma unroll
      for (int rr = 0; rr < 4; ++rr) mx = fmaxf(mx, st[kf][rr]);
    mx = fmaxf(mx, __shfl_xor(mx, 16, 64));
    mx = fmaxf(mx, __shfl_xor(mx, 32, 64));
    const float m_new = fmaxf(m_run, mx);
    const float alpha = EXP2F((m_run - m_new) * CSC);

    float p[4][4];
    float tsum = 0.f;
#pragma unroll
    for (int kf = 0; kf < 4; ++kf)
#pragma unroll
      for (int rr = 0; rr < 4; ++rr) {
        p[kf][rr] = EXP2F((st[kf][rr] - m_new) * CSC);
        tsum += p[kf][rr];
      }
    tsum += __shfl_xor(tsum, 16, 64);
    tsum += __shfl_xor(tsum, 32, 64);
    l_run = l_run * alpha + tsum;
    m_run = m_new;

#pragma unroll
    for (int rr = 0; rr < 4; ++rr) {
      const float ar = __shfl(alpha, quad * 4 + rr, 64);
#pragma unroll
      for (int nc = 0; nc < 8; ++nc) acc[nc][rr] *= ar;
    }

    short* pw = &Plds[(w * 16 + l15) * PT_STR];
#pragma unroll
    for (int kf = 0; kf < 4; ++kf) {
      uint2 u;
      u.x = bfpack2(p[kf][0], p[kf][1]);
      u.y = bfpack2(p[kf][2], p[kf][3]);
      *(uint2*)(&pw[kf * 16 + quad * 4]) = u;
    }
    __asm__ __volatile__("" ::: "memory");
    short8 pa0 = *(const short8*)(&pw[quad * 8]);
    short8 pa1 = *(const short8*)(&pw[32 + quad * 8]);

#pragma unroll
    for (int nc = 0; nc < 8; ++nc) {
      short8 bv0 = *(const short8*)(&Vtlds[(nc * 16 + l15) * VT_STR + quad * 8]);
      acc[nc] = __builtin_amdgcn_mfma_f32_16x16x32_bf16(pa0, bv0, acc[nc], 0, 0, 0);
      short8 bv1 = *(const short8*)(&Vtlds[(nc * 16 + l15) * VT_STR + 32 + quad * 8]);
      acc[nc] = __builtin_amdgcn_mfma_f32_16x16x32_bf16(pa1, bv1, acc[nc], 0, 0, 0);
    }
    __syncthreads();
  }

#pragma unroll
  for (int rr = 0; rr < 4; ++rr) {
    const float lr  = __shfl(l_run, quad * 4 + rr, 64);
    const float inv = 1.0f / lr;
    const int qout  = q0 + w * 16 + quad * 4 + rr;
    float* op = O + (size_t)(b * S_LEN + qout) * D_K + l15;
#pragma unroll
    for (int nc = 0; nc < 8; ++nc) op[nc * 16] = acc[nc][rr] * inv;
  }
}

// ======================= launch =======================

extern "C" void kernel_launch(void* const* d_in, const int* in_sizes, int n_in,
                              void* d_out, int out_size, void* d_ws, size_t ws_size,
                              hipStream_t stream) {
  const float* Q = (const float*)d_in[0];
  const float* K = (const float*)d_in[1];
  const float* V = (const float*)d_in[2];
  float* O = (float*)d_out;

  const size_t elems = (size_t)B_SZ * S_LEN * D_K;   // 4.19M

  // ws layout (bytes):
  //   0          : counter (int, 256B slot)
  //   256        : ml    [1152 slots][128 q][m,l]      =  1,179,648
  //   1,179,904  : partO [1152 slots][128 q][128 d]f32 = 75,497,472
  //   76,677,376 : Kb tile-images bf16                 =  8,388,608
  //   85,065,984 : Vt tile-images bf16                 =  8,388,608
  //   need ~93.5 MB
  const size_t off_ml = 256;
  const size_t off_po = off_ml + (size_t)NCHUNK * 256 * 4;
  const size_t off_kb = off_po + (size_t)NCHUNK * 16384 * 4;
  const size_t off_vt = off_kb + elems * 2;
  const size_t need   = off_vt + elems * 2;

  if (ws_size >= need) {
    char* ws = (char*)d_ws;
    int*            cnt = (int*)ws;
    float*          mlp = (float*)(ws + off_ml);
    float*          po  = (float*)(ws + off_po);
    unsigned short* Kbp = (unsigned short*)(ws + off_kb);
    unsigned short* Vtp = (unsigned short*)(ws + off_vt);

    prep<<<dim3(B_SZ * 64), dim3(256), 0, stream>>>(K, V, Kbp, Vtp, cnt);
    attn_worker<<<dim3(768), dim3(256), 0, stream>>>(Q, Kbp, Vtp, cnt, mlp, po);
    attn_combine<<<dim3(256), dim3(256), 0, stream>>>(mlp, po, O);
  } else {
    attn_fwd_fb<<<dim3(512), dim3(256), 0, stream>>>(Q, K, V, O);
  }
}

// Round 13
// 188.601 us; speedup vs baseline: 1.2652x; 1.2652x over previous
//
#include <hip/hip_runtime.h>

#define B_SZ   8
#define S_LEN  4096
#define D_K    128
#define KB     64      // keys per step
#define CH     8       // steps per chunk
// 128-q tiles (32/batch), tile q needs 2q+2 steps; chunks of <=8 steps:
// sum over q of ceil((2q+2)/8) = 144 per batch -> 1152 chunks total.
#define NCHUNK 1152
#define NC(q)  (((q) + 4) >> 2)   // ceil((q+1)/4) = chunks for tile q

typedef short  short8  __attribute__((ext_vector_type(8)));
typedef float  floatx4 __attribute__((ext_vector_type(4)));

// raw v_exp_f32 (2^x) where available; args are always <= 0 here (no range issues)
#if defined(__has_builtin)
#if __has_builtin(__builtin_amdgcn_exp2f)
#define EXP2F(x) __builtin_amdgcn_exp2f(x)
#endif
#endif
#ifndef EXP2F
#define EXP2F(x) exp2f(x)
#endif

__device__ __forceinline__ unsigned bfround(float x) {
  unsigned u = __builtin_bit_cast(unsigned, x);
  return (u + 0x7fffu + ((u >> 16) & 1u)) >> 16;
}
__device__ __forceinline__ unsigned bfpack2(float a, float b) {
  return bfround(a) | (bfround(b) << 16);
}
// single-instruction RTNE pack (hot loop only; numerics validated R1-R12)
__device__ __forceinline__ unsigned cvtpk(float lo, float hi) {
  unsigned r;
  asm("v_cvt_pk_bf16_f32 %0, %1, %2" : "=v"(r) : "v"(lo), "v"(hi));
  return r;
}

// NOTE (R6): permlane16/32_swap reductions failed correctness. __shfl_xor only.
// NOTE (R9/R12): empirical __launch_bounds__ cap law on this toolchain:
// VGPR cap ~= 512/(2*arg) regardless of block size. arg=2 -> 128 (fits the
// ~104 working set); arg=3 -> 84 (R1,R12: spill); arg=4@512thr -> 64 (R9:
// catastrophic). ALWAYS use arg=2 for this kernel. The min-blocks hint does
// not limit upward residency: at 104 VGPR, LDS (49.7KB) is the binding
// constraint -> 3 blocks/CU.

// Async global->LDS DMA, 16B per lane (wave writes 1024B contiguous LDS).
__device__ __forceinline__ void dma16(const void* g, const void* l) {
  __builtin_amdgcn_global_load_lds(
      (__attribute__((address_space(1))) unsigned int*)(unsigned long long)g,
      (__attribute__((address_space(3))) unsigned int*)(unsigned int)(unsigned long long)l,
      16, 0, 0);
}

// ======================= pre-pass: tile-image builder (R3-R12 proven) =======================
// One block per (b, step s): K and V^T as 16KB tile IMAGES with the XOR
// bank-swizzle baked in (byte ^= ((row&7)<<4)); worker DMAs them linearly.
// Block 0 zeroes the chunk counter.

__global__ __launch_bounds__(256)
void prep(const float* __restrict__ K, const float* __restrict__ V,
          unsigned short* __restrict__ Kb, unsigned short* __restrict__ Vt,
          int* __restrict__ cnt) {
  __shared__ float tile[64][129];
  const int tid = threadIdx.x;
  const int bid = blockIdx.x;         // b*64 + s
  if (bid == 0 && tid == 0) *cnt = 0;
  const int b   = bid >> 6;
  const int s   = bid & 63;
  const int kt  = s * 64;

  // ---- K tile image ----
  {
    const int r  = tid >> 2;
    const int cq = tid & 3;
    const float* kp = K + (size_t)(b * S_LEN + kt + r) * D_K + cq * 32;
    unsigned short* kdst = Kb + (size_t)bid * 8192 + r * 128;
    const int xr = (r & 7) << 4;
#pragma unroll
    for (int jj = 0; jj < 4; ++jj) {
      float4 f0 = *(const float4*)(kp + jj * 8);
      float4 f1 = *(const float4*)(kp + jj * 8 + 4);
      uint4 u;
      u.x = bfpack2(f0.x, f0.y);
      u.y = bfpack2(f0.z, f0.w);
      u.z = bfpack2(f1.x, f1.y);
      u.w = bfpack2(f1.z, f1.w);
      const int o = (cq * 64 + jj * 16) ^ xr;
      *(uint4*)(kdst + (o >> 1)) = u;
    }
  }

  // ---- V tile: load to LDS f32 ----
  {
    const int k  = tid >> 2;
    const int cq = tid & 3;
    const float* vp = V + (size_t)(b * S_LEN + kt + k) * D_K + cq * 32;
#pragma unroll
    for (int i = 0; i < 8; ++i) {
      float4 f = *(const float4*)(vp + i * 4);
      tile[k][cq * 32 + i * 4]     = f.x;
      tile[k][cq * 32 + i * 4 + 1] = f.y;
      tile[k][cq * 32 + i * 4 + 2] = f.z;
      tile[k][cq * 32 + i * 4 + 3] = f.w;
    }
  }
  __syncthreads();

  // ---- V^T tile image (transposed + swizzled) ----
  {
    const int d = tid >> 1;
    const int h = tid & 1;
    unsigned short* vdst = Vt + (size_t)bid * 8192 + d * 64;
    const int xr = (d & 7) << 4;
#pragma unroll
    for (int jj = 0; jj < 4; ++jj) {
      const int k0 = h * 32 + jj * 8;
      uint4 u;
      u.x = bfpack2(tile[k0 + 0][d], tile[k0 + 1][d]);
      u.y = bfpack2(tile[k0 + 2][d], tile[k0 + 3][d]);
      u.z = bfpack2(tile[k0 + 4][d], tile[k0 + 5][d]);
      u.w = bfpack2(tile[k0 + 6][d], tile[k0 + 7][d]);
      const int o = (h * 64 + jj * 16) ^ xr;
      *(uint4*)(vdst + (o >> 1)) = u;
    }
  }
}

// ======================= worker kernel =======================
// R13 = R12 with the launch-bounds fix (arg 3 -> 2; see cap-law note above).
// R7 skeleton (4 waves, 128-q tile, atomic LPT stealing) with LDS cut to
// 49,152B -> 3 blocks/CU = 3 waves/SIMD (+50% TLP vs R7): K double-buffered
// (2x16KB), V SINGLE-buffered (16KB, staged one step ahead), P through the
// dead K buffer. Per-step wait order (2 barriers, race-checked):
//   QKT(s) -> vmcnt(0) -> barrier1   [K[cur] becomes P scratch; all waves'
//                                     V(s)/K(s+1) DMAs landed -> visible]
//   softmax + P roundtrip + PV(s) -> lgkmcnt(0) -> barrier2
//   STAGE K(s+2) -> K[cur], V(s+1) -> V     [no wait; next step's vmcnt covers]
// CH=8 chunks (1152) over grid 768 = single-generation stealing schedule.

__global__ __launch_bounds__(256, 2)
void attn_worker(const float* __restrict__ Q, const unsigned short* __restrict__ Kb,
                 const unsigned short* __restrict__ Vt, int* __restrict__ cnt,
                 float* __restrict__ ml, float* __restrict__ pO) {
  __shared__ __align__(16) short Klds[2][8192];   // 2 x 16KB (also P scratch)
  __shared__ __align__(16) short Vtlds[8192];     // 16KB single buffer
  __shared__ int s_chunk;

  const int tid  = threadIdx.x;
  const int lane = tid & 63;
  const int w    = tid >> 6;        // wave 0..3
  const int l15  = lane & 15;
  const int quad = lane >> 4;
  const int xk   = (l15 & 7) << 3;  // short-index XOR for swizzled LDS reads

  const float CSC = 0.12752041f;    // log2(e)/sqrt(128)

  for (;;) {
    if (tid == 0) s_chunk = atomicAdd(cnt, 1);
    __syncthreads();
    const int c = s_chunk;
    if (c >= NCHUNK) break;

    // ---- decode: b = c&7; tiles enumerated q=31 down (LPT) ----
    const int b = c & 7;
    int q = 31, r = c >> 3;           // r in [0,144)
    while (r >= NC(q)) { r -= NC(q); --q; }
    const int j  = r;
    const int q0 = q * 128;
    const int s0 = j * CH;
    const int s1 = min(s0 + CH, 2 * q + 2);

    // ---- Q fragments for 2 subtiles (B-operand: n=l15=query, k=quad*8+i=d) ----
    short8 bq[2][4];
    int qg[2];
#pragma unroll
    for (int sub = 0; sub < 2; ++sub) {
      qg[sub] = q0 + w * 32 + sub * 16 + l15;
      const float* qrow = Q + (size_t)(b * S_LEN + qg[sub]) * D_K + quad * 8;
#pragma unroll
      for (int kd = 0; kd < 4; ++kd) {
        float4 f0 = *(const float4*)(qrow + kd * 32);
        float4 f1 = *(const float4*)(qrow + kd * 32 + 4);
        union { short8 s; unsigned u[4]; } tt;
        tt.u[0] = bfpack2(f0.x, f0.y);
        tt.u[1] = bfpack2(f0.z, f0.w);
        tt.u[2] = bfpack2(f1.x, f1.y);
        tt.u[3] = bfpack2(f1.z, f1.w);
        bq[sub][kd] = tt.s;
      }
    }

    floatx4 acc[2][8];
#pragma unroll
    for (int sub = 0; sub < 2; ++sub)
#pragma unroll
      for (int nc = 0; nc < 8; ++nc) acc[sub][nc] = (floatx4){0.f, 0.f, 0.f, 0.f};
    float m_run[2] = {-1e30f, -1e30f}, l_run[2] = {0.f, 0.f};

    const unsigned short* kb0 = Kb + (size_t)b * 64 * 8192;   // tile images
    const unsigned short* vb0 = Vt + (size_t)b * 64 * 8192;
    const int lo = lane * 8;            // lane*16B in shorts

    // each wave stages its quarter (4KB) of a 16KB tile = 4 dma16
#define STAGE_K(BUF, S)                                                        \
    do {                                                                       \
      const unsigned short* kg_ = kb0 + (size_t)(S) * 8192 + w * 2048 + lo;    \
      short* kl_ = &Klds[BUF][w * 2048];                                       \
      _Pragma("unroll")                                                        \
      for (int i_ = 0; i_ < 4; ++i_) dma16(kg_ + i_ * 512, kl_ + i_ * 512);    \
    } while (0)
#define STAGE_V(S)                                                             \
    do {                                                                       \
      const unsigned short* vg_ = vb0 + (size_t)(S) * 8192 + w * 2048 + lo;    \
      short* vl_ = &Vtlds[w * 2048];                                           \
      _Pragma("unroll")                                                        \
      for (int i_ = 0; i_ < 4; ++i_) dma16(vg_ + i_ * 512, vl_ + i_ * 512);    \
    } while (0)

    // ---- prologue: K(s0), K(s0+1), V(s0); wait all, barrier ----
    STAGE_K(s0 & 1, s0);
    if (s0 + 1 < s1) STAGE_K((s0 + 1) & 1, s0 + 1);
    STAGE_V(s0);
    asm volatile("s_waitcnt vmcnt(0)" ::: "memory");
    __builtin_amdgcn_s_barrier();
    __builtin_amdgcn_sched_barrier(0);

    for (int s = s0; s < s1; ++s) {
      const int kt  = s * KB;
      const int cur = s & 1;
      const short* Kl = &Klds[cur][0];
      const bool act = (kt <= q0 + w * 32 + 31);   // wave fully masked beyond

      floatx4 st[2][4];
      if (act) {
        // ---- S^T = K*Q^T for both subtiles; each A-frag read used twice ----
        __builtin_amdgcn_s_setprio(1);
#pragma unroll
        for (int kf = 0; kf < 4; ++kf) {
          floatx4 c0 = (floatx4){0.f, 0.f, 0.f, 0.f};
          floatx4 c1 = (floatx4){0.f, 0.f, 0.f, 0.f};
#pragma unroll
          for (int kd = 0; kd < 4; ++kd) {
            short8 a = *(const short8*)(&Kl[((kf * 16 + l15) << 7) + ((kd * 32 + quad * 8) ^ xk)]);
            c0 = __builtin_amdgcn_mfma_f32_16x16x32_bf16(a, bq[0][kd], c0, 0, 0, 0);
            c1 = __builtin_amdgcn_mfma_f32_16x16x32_bf16(a, bq[1][kd], c1, 0, 0, 0);
          }
          st[0][kf] = c0;
          st[1][kf] = c1;
        }
        __builtin_amdgcn_s_setprio(0);

        // ---- causal mask (boundary subtiles only) ----
#pragma unroll
        for (int sub = 0; sub < 2; ++sub) {
          if (kt + 63 > q0 + w * 32 + sub * 16) {
#pragma unroll
            for (int kf = 0; kf < 4; ++kf)
#pragma unroll
              for (int rr = 0; rr < 4; ++rr) {
                int key = kt + kf * 16 + quad * 4 + rr;
                if (key > qg[sub]) st[sub][kf][rr] = -1e30f;
              }
          }
        }
      }

      // own DMAs (V(s), K(s+1)) done; barrier => ALL waves' DMAs visible AND
      // K[cur] fully consumed block-wide (becomes P scratch).
      asm volatile("s_waitcnt vmcnt(0)" ::: "memory");
      __builtin_amdgcn_s_barrier();
      __builtin_amdgcn_sched_barrier(0);

      short8 pa[2][2];
      if (act) {
        // ---- online softmax + P roundtrip (through Klds[cur]) per subtile ----
        short* pw = &Klds[cur][(w * 16 + l15) << 6];   // wave-private 64-short row
#pragma unroll
        for (int sub = 0; sub < 2; ++sub) {
          float mx = st[sub][0][0];
#pragma unroll
          for (int kf = 0; kf < 4; ++kf)
#pragma unroll
            for (int rr = 0; rr < 4; ++rr) mx = fmaxf(mx, st[sub][kf][rr]);
          mx = fmaxf(mx, __shfl_xor(mx, 16, 64));
          mx = fmaxf(mx, __shfl_xor(mx, 32, 64));
          const float m_new = fmaxf(m_run[sub], mx);
          const bool  grow  = __any(m_new > m_run[sub]);

          float p[4][4];
          float tsum = 0.f;
#pragma unroll
          for (int kf = 0; kf < 4; ++kf)
#pragma unroll
            for (int rr = 0; rr < 4; ++rr) {
              p[kf][rr] = EXP2F((st[sub][kf][rr] - m_new) * CSC);
              tsum += p[kf][rr];
            }
          tsum += __shfl_xor(tsum, 16, 64);
          tsum += __shfl_xor(tsum, 32, 64);

          if (grow) {
            const float alpha = EXP2F((m_run[sub] - m_new) * CSC);
            l_run[sub] = l_run[sub] * alpha + tsum;
#pragma unroll
            for (int rr = 0; rr < 4; ++rr) {
              const float ar = __shfl(alpha, quad * 4 + rr, 64);
#pragma unroll
              for (int nc = 0; nc < 8; ++nc) acc[sub][nc][rr] *= ar;
            }
          } else {
            l_run[sub] = l_run[sub] + tsum;   // m_new == m_run for every query
          }
          m_run[sub] = m_new;

          // P: C-layout -> A-layout; XOR-swizzled stride-64 rows (in-order per wave)
#pragma unroll
          for (int kf = 0; kf < 4; ++kf) {
            uint2 u;
            u.x = cvtpk(p[kf][0], p[kf][1]);
            u.y = cvtpk(p[kf][2], p[kf][3]);
            *(uint2*)(&pw[(kf * 16 + quad * 4) ^ xk]) = u;
          }
          __asm__ __volatile__("" ::: "memory");
          pa[sub][0] = *(const short8*)(&pw[(quad * 8) ^ xk]);
          pa[sub][1] = *(const short8*)(&pw[(32 + quad * 8) ^ xk]);
          __asm__ __volatile__("" ::: "memory");
        }

        // ---- O += P*V ; each B-frag read used by both subtiles ----
        __builtin_amdgcn_s_setprio(1);
#pragma unroll
        for (int nc = 0; nc < 8; ++nc) {
          short8 bv0 = *(const short8*)(&Vtlds[((nc * 16 + l15) << 6) + ((quad * 8) ^ xk)]);
          short8 bv1 = *(const short8*)(&Vtlds[((nc * 16 + l15) << 6) + ((32 + quad * 8) ^ xk)]);
          acc[0][nc] = __builtin_amdgcn_mfma_f32_16x16x32_bf16(pa[0][0], bv0, acc[0][nc], 0, 0, 0);
          acc[0][nc] = __builtin_amdgcn_mfma_f32_16x16x32_bf16(pa[0][1], bv1, acc[0][nc], 0, 0, 0);
          acc[1][nc] = __builtin_amdgcn_mfma_f32_16x16x32_bf16(pa[1][0], bv0, acc[1][nc], 0, 0, 0);
          acc[1][nc] = __builtin_amdgcn_mfma_f32_16x16x32_bf16(pa[1][1], bv1, acc[1][nc], 0, 0, 0);
        }
        __builtin_amdgcn_s_setprio(0);
      }

      // ---- all P-scratch & V reads done -> stage next ----
      asm volatile("s_waitcnt lgkmcnt(0)" ::: "memory");
      __builtin_amdgcn_s_barrier();
      __builtin_amdgcn_sched_barrier(0);
      if (s + 2 < s1) STAGE_K(cur, s + 2);
      if (s + 1 < s1) STAGE_V(s + 1);
      // no wait here: next step's vmcnt(0) (after QKT) covers these
    }
#undef STAGE_K
#undef STAGE_V

    // ---- partial epilogue: unnormalized O + (m,l); slot == c ----
    float* po = pO + (size_t)c * 16384;
#pragma unroll
    for (int sub = 0; sub < 2; ++sub) {
#pragma unroll
      for (int rr = 0; rr < 4; ++rr) {
        const int qrow = w * 32 + sub * 16 + quad * 4 + rr;
        float* op = po + qrow * D_K + l15;
#pragma unroll
        for (int nc = 0; nc < 8; ++nc) op[nc * 16] = acc[sub][nc][rr];
      }
      if (quad == 0) {
        const int qrow = w * 32 + sub * 16 + l15;
        ml[(size_t)c * 256 + qrow * 2]     = m_run[sub];
        ml[(size_t)c * 256 + qrow * 2 + 1] = l_run[sub];
      }
    }
  }
}

// ======================= combine kernel =======================
// 256 blocks = b*32 + q (128-q tiles); up to 8 partials per tile.

__global__ __launch_bounds__(256)
void attn_combine(const float* __restrict__ ml, const float* __restrict__ pO,
                  float* __restrict__ O) {
  const int t = blockIdx.x;           // 0..255 = b*32 + q
  const int b = t >> 5;
  const int q = t & 31;
  const float CSC = 0.12752041f;

  const int tid = threadIdx.x;
  const int ql  = tid >> 1;           // 0..127
  const int dh  = (tid & 1) * 64;     // d-span of 64 floats

  int cum = 0;
  for (int tq = 31; tq > q; --tq) cum += NC(tq);
  const int ncb = NC(q);              // 1..8

  float m[8], l[8], wgt[8];
  float M = -1e30f;
#pragma unroll
  for (int i = 0; i < 8; ++i) {
    if (i < ncb) {
      const size_t slot = (size_t)((cum + i) << 3 | b);
      m[i] = ml[slot * 256 + ql * 2];
      l[i] = ml[slot * 256 + ql * 2 + 1];
      M = fmaxf(M, m[i]);
    }
  }
  float L = 0.f;
#pragma unroll
  for (int i = 0; i < 8; ++i)
    if (i < ncb) { wgt[i] = EXP2F((m[i] - M) * CSC); L += wgt[i] * l[i]; }
  const float inv = 1.0f / L;

  float4 out[16];
#pragma unroll
  for (int v = 0; v < 16; ++v) out[v] = make_float4(0.f, 0.f, 0.f, 0.f);
#pragma unroll
  for (int i = 0; i < 8; ++i) {
    if (i < ncb) {
      const size_t slot = (size_t)((cum + i) << 3 | b);
      const float* src = pO + slot * 16384 + ql * D_K + dh;
      const float wj = wgt[i];
#pragma unroll
      for (int v = 0; v < 16; ++v) {
        float4 f = *(const float4*)(src + v * 4);
        out[v].x += wj * f.x;  out[v].y += wj * f.y;
        out[v].z += wj * f.z;  out[v].w += wj * f.w;
      }
    }
  }
  float* dst = O + ((size_t)(b * S_LEN) + q * 128 + ql) * D_K + dh;
#pragma unroll
  for (int v = 0; v < 16; ++v) {
    *(float4*)(dst + v * 4) = make_float4(out[v].x * inv, out[v].y * inv,
                                          out[v].z * inv, out[v].w * inv);
  }
}

// ======================= fallback (known-good, ws-too-small path) =======================

#define KT_STR 136
#define VT_STR 72
#define PT_STR 72

__global__ __launch_bounds__(256, 2)
void attn_fwd_fb(const float* __restrict__ Q, const float* __restrict__ K,
                 const float* __restrict__ V, float* __restrict__ O) {
  __shared__ __align__(16) short Klds[KB * KT_STR];
  __shared__ __align__(16) short Vtlds[D_K * VT_STR];
  __shared__ __align__(16) short Plds[4 * 16 * PT_STR];

  const int tid  = threadIdx.x;
  const int lane = tid & 63;
  const int w    = tid >> 6;
  const int l15  = lane & 15;
  const int quad = lane >> 4;

  const int bid = blockIdx.x;
  const int b   = bid & 7;
  const int qi  = 63 - (bid >> 3);
  const int q0  = qi * 64;

  const float CSC = 0.12752041f;

  const int    qg   = q0 + w * 16 + l15;
  const float* qrow = Q + (size_t)(b * S_LEN + qg) * D_K + quad * 8;
  short8 bq[4];
#pragma unroll
  for (int kd = 0; kd < 4; ++kd) {
    float4 f0 = *(const float4*)(qrow + kd * 32);
    float4 f1 = *(const float4*)(qrow + kd * 32 + 4);
    union { short8 s; unsigned u[4]; } t;
    t.u[0] = bfpack2(f0.x, f0.y);
    t.u[1] = bfpack2(f0.z, f0.w);
    t.u[2] = bfpack2(f1.x, f1.y);
    t.u[3] = bfpack2(f1.z, f1.w);
    bq[kd] = t.s;
  }

  floatx4 acc[8];
#pragma unroll
  for (int nc = 0; nc < 8; ++nc) acc[nc] = (floatx4){0.f, 0.f, 0.f, 0.f};
  float m_run = -1e30f, l_run = 0.f;

  const int d4 = tid & 31;
  const int kq = tid >> 5;
  const int nsteps = qi + 1;

  for (int s = 0; s < nsteps; ++s) {
    const int kt = s * KB;
#pragma unroll
    for (int r2 = 0; r2 < 2; ++r2) {
      const int row = r2 * 32 + kq * 4;
      const float* kp = K + (size_t)(b * S_LEN + kt + row) * D_K + d4 * 4;
      const float* vp = V + (size_t)(b * S_LEN + kt + row) * D_K + d4 * 4;
      float4 fk[4], fv[4];
#pragma unroll
      for (int i = 0; i < 4; ++i) {
        fk[i] = *(const float4*)(kp + i * D_K);
        fv[i] = *(const float4*)(vp + i * D_K);
      }
#pragma unroll
      for (int i = 0; i < 4; ++i) {
        uint2 u;
        u.x = bfpack2(fk[i].x, fk[i].y);
        u.y = bfpack2(fk[i].z, fk[i].w);
        *(uint2*)(&Klds[(row + i) * KT_STR + d4 * 4]) = u;
      }
#pragma unroll
      for (int c = 0; c < 4; ++c) {
        float e0 = ((const float*)&fv[0])[c];
        float e1 = ((const float*)&fv[1])[c];
        float e2 = ((const float*)&fv[2])[c];
        float e3 = ((const float*)&fv[3])[c];
        uint2 u;
        u.x = bfpack2(e0, e1);
        u.y = bfpack2(e2, e3);
        *(uint2*)(&Vtlds[(d4 * 4 + c) * VT_STR + row]) = u;
      }
    }
    __syncthreads();

    floatx4 st[4];
#pragma unroll
    for (int kf = 0; kf < 4; ++kf) {
      floatx4 cc = (floatx4){0.f, 0.f, 0.f, 0.f};
#pragma unroll
      for (int kd = 0; kd < 4; ++kd) {
        short8 a = *(const short8*)(&Klds[(kf * 16 + l15) * KT_STR + kd * 32 + quad * 8]);
        cc = __builtin_amdgcn_mfma_f32_16x16x32_bf16(a, bq[kd], cc, 0, 0, 0);
      }
      st[kf] = cc;
    }

    if (s == nsteps - 1) {
#pragma unroll
      for (int kf = 0; kf < 4; ++kf)
#pragma unroll
        for (int rr = 0; rr < 4; ++rr) {
          int key = kt + kf * 16 + quad * 4 + rr;
          if (key > qg) st[kf][rr] = -1e30f;
        }
    }

    float mx = st[0][0];
#pragma unroll
    for (int kf = 0; kf < 4; ++kf)
#pragma unroll
      for (int rr = 0; rr < 4; ++rr) mx = fmaxf(mx, st[kf][rr]);
    mx = fmaxf(mx, __shfl_xor(mx, 16, 64));
    mx = fmaxf(mx, __shfl_xor(mx, 32, 64));
    const float m_new = fmaxf(m_run, mx);
    const float alpha = EXP2F((m_run - m_new) * CSC);

    float p[4][4];
    float tsum = 0.f;
#pragma unroll
    for (int kf = 0; kf < 4; ++kf)
#pragma unroll
      for (int rr = 0; rr < 4; ++rr) {
        p[kf][rr] = EXP2F((st[kf][rr] - m_new) * CSC);
        tsum += p[kf][rr];
      }
    tsum += __shfl_xor(tsum, 16, 64);
    tsum += __shfl_xor(tsum, 32, 64);
    l_run = l_run * alpha + tsum;
    m_run = m_new;

#pragma unroll
    for (int rr = 0; rr < 4; ++rr) {
      const float ar = __shfl(alpha, quad * 4 + rr, 64);
#pragma unroll
      for (int nc = 0; nc < 8; ++nc) acc[nc][rr] *= ar;
    }

    short* pw = &Plds[(w * 16 + l15) * PT_STR];
#pragma unroll
    for (int kf = 0; kf < 4; ++kf) {
      uint2 u;
      u.x = bfpack2(p[kf][0], p[kf][1]);
      u.y = bfpack2(p[kf][2], p[kf][3]);
      *(uint2*)(&pw[kf * 16 + quad * 4]) = u;
    }
    __asm__ __volatile__("" ::: "memory");
    short8 pa0 = *(const short8*)(&pw[quad * 8]);
    short8 pa1 = *(const short8*)(&pw[32 + quad * 8]);

#pragma unroll
    for (int nc = 0; nc < 8; ++nc) {
      short8 bv0 = *(const short8*)(&Vtlds[(nc * 16 + l15) * VT_STR + quad * 8]);
      acc[nc] = __builtin_amdgcn_mfma_f32_16x16x32_bf16(pa0, bv0, acc[nc], 0, 0, 0);
      short8 bv1 = *(const short8*)(&Vtlds[(nc * 16 + l15) * VT_STR + 32 + quad * 8]);
      acc[nc] = __builtin_amdgcn_mfma_f32_16x16x32_bf16(pa1, bv1, acc[nc], 0, 0, 0);
    }
    __syncthreads();
  }

#pragma unroll
  for (int rr = 0; rr < 4; ++rr) {
    const float lr  = __shfl(l_run, quad * 4 + rr, 64);
    const float inv = 1.0f / lr;
    const int qout  = q0 + w * 16 + quad * 4 + rr;
    float* op = O + (size_t)(b * S_LEN + qout) * D_K + l15;
#pragma unroll
    for (int nc = 0; nc < 8; ++nc) op[nc * 16] = acc[nc][rr] * inv;
  }
}

// ======================= launch =======================

extern "C" void kernel_launch(void* const* d_in, const int* in_sizes, int n_in,
                              void* d_out, int out_size, void* d_ws, size_t ws_size,
                              hipStream_t stream) {
  const float* Q = (const float*)d_in[0];
  const float* K = (const float*)d_in[1];
  const float* V = (const float*)d_in[2];
  float* O = (float*)d_out;

  const size_t elems = (size_t)B_SZ * S_LEN * D_K;   // 4.19M

  // ws layout (bytes):
  //   0          : counter (int, 256B slot)
  //   256        : ml    [1152 slots][128 q][m,l]      =  1,179,648
  //   1,179,904  : partO [1152 slots][128 q][128 d]f32 = 75,497,472
  //   76,677,376 : Kb tile-images bf16                 =  8,388,608
  //   85,065,984 : Vt tile-images bf16                 =  8,388,608
  //   need ~93.5 MB
  const size_t off_ml = 256;
  const size_t off_po = off_ml + (size_t)NCHUNK * 256 * 4;
  const size_t off_kb = off_po + (size_t)NCHUNK * 16384 * 4;
  const size_t off_vt = off_kb + elems * 2;
  const size_t need   = off_vt + elems * 2;

  if (ws_size >= need) {
    char* ws = (char*)d_ws;
    int*            cnt = (int*)ws;
    float*          mlp = (float*)(ws + off_ml);
    float*          po  = (float*)(ws + off_po);
    unsigned short* Kbp = (unsigned short*)(ws + off_kb);
    unsigned short* Vtp = (unsigned short*)(ws + off_vt);

    prep<<<dim3(B_SZ * 64), dim3(256), 0, stream>>>(K, V, Kbp, Vtp, cnt);
    attn_worker<<<dim3(768), dim3(256), 0, stream>>>(Q, Kbp, Vtp, cnt, mlp, po);
    attn_combine<<<dim3(256), dim3(256), 0, stream>>>(mlp, po, O);
  } else {
    attn_fwd_fb<<<dim3(512), dim3(256), 0, stream>>>(Q, K, V, O);
  }
}

// Round 14
// 184.090 us; speedup vs baseline: 1.2962x; 1.0245x over previous
//
#include <hip/hip_runtime.h>

#define B_SZ   8
#define S_LEN  4096
#define D_K    128
#define KB     64      // keys per step
#define CH     8       // steps per chunk
// 128-q tiles (32/batch), tile q needs 2q+2 steps; chunks of <=8 steps:
// sum over q of ceil((2q+2)/8) = 144 per batch -> 1152 chunks total.
#define NCHUNK 1152
#define NC(q)  (((q) + 4) >> 2)   // ceil((q+1)/4) = chunks for tile q

typedef short  short8  __attribute__((ext_vector_type(8)));
typedef float  floatx4 __attribute__((ext_vector_type(4)));

// raw v_exp_f32 (2^x) where available; args are always <= 0 here
#if defined(__has_builtin)
#if __has_builtin(__builtin_amdgcn_exp2f)
#define EXP2F(x) __builtin_amdgcn_exp2f(x)
#endif
#endif
#ifndef EXP2F
#define EXP2F(x) exp2f(x)
#endif

__device__ __forceinline__ unsigned bfround(float x) {
  unsigned u = __builtin_bit_cast(unsigned, x);
  return (u + 0x7fffu + ((u >> 16) & 1u)) >> 16;
}
__device__ __forceinline__ unsigned bfpack2(float a, float b) {
  return bfround(a) | (bfround(b) << 16);
}
__device__ __forceinline__ float bf2f(unsigned short s) {
  return __builtin_bit_cast(float, ((unsigned)s) << 16);
}
// single-instruction RTNE pack (hot loop only; numerics validated R1-R13)
__device__ __forceinline__ unsigned cvtpk(float lo, float hi) {
  unsigned r;
  asm("v_cvt_pk_bf16_f32 %0, %1, %2" : "=v"(r) : "v"(lo), "v"(hi));
  return r;
}

// NOTE (R6): permlane16/32_swap reductions failed correctness. __shfl_xor only.
// NOTE (R9/R12): empirical __launch_bounds__ cap law on this toolchain:
// VGPR cap ~= 512/(2*arg). arg=2 -> 128 (fits ~112 working set); arg=3 -> 84
// (R1,R12: spill); arg=4@512thr -> 64 (R9: catastrophic). ALWAYS arg=2 here.

// Async global->LDS DMA, 16B per lane (wave writes 1024B contiguous LDS).
__device__ __forceinline__ void dma16(const void* g, const void* l) {
  __builtin_amdgcn_global_load_lds(
      (__attribute__((address_space(1))) unsigned int*)(unsigned long long)g,
      (__attribute__((address_space(3))) unsigned int*)(unsigned int)(unsigned long long)l,
      16, 0, 0);
}

// ======================= pre-pass: tile-image builder (R3-R13 proven) =======================
// One block per (b, step s): K and V^T as 16KB tile IMAGES with the XOR
// bank-swizzle baked in (byte ^= ((row&7)<<4)); worker DMAs them linearly.
// Block 0 zeroes the chunk counter.

__global__ __launch_bounds__(256)
void prep(const float* __restrict__ K, const float* __restrict__ V,
          unsigned short* __restrict__ Kb, unsigned short* __restrict__ Vt,
          int* __restrict__ cnt) {
  __shared__ float tile[64][129];
  const int tid = threadIdx.x;
  const int bid = blockIdx.x;         // b*64 + s
  if (bid == 0 && tid == 0) *cnt = 0;
  const int b   = bid >> 6;
  const int s   = bid & 63;
  const int kt  = s * 64;

  // ---- K tile image ----
  {
    const int r  = tid >> 2;
    const int cq = tid & 3;
    const float* kp = K + (size_t)(b * S_LEN + kt + r) * D_K + cq * 32;
    unsigned short* kdst = Kb + (size_t)bid * 8192 + r * 128;
    const int xr = (r & 7) << 4;
#pragma unroll
    for (int jj = 0; jj < 4; ++jj) {
      float4 f0 = *(const float4*)(kp + jj * 8);
      float4 f1 = *(const float4*)(kp + jj * 8 + 4);
      uint4 u;
      u.x = bfpack2(f0.x, f0.y);
      u.y = bfpack2(f0.z, f0.w);
      u.z = bfpack2(f1.x, f1.y);
      u.w = bfpack2(f1.z, f1.w);
      const int o = (cq * 64 + jj * 16) ^ xr;
      *(uint4*)(kdst + (o >> 1)) = u;
    }
  }

  // ---- V tile: load to LDS f32 ----
  {
    const int k  = tid >> 2;
    const int cq = tid & 3;
    const float* vp = V + (size_t)(b * S_LEN + kt + k) * D_K + cq * 32;
#pragma unroll
    for (int i = 0; i < 8; ++i) {
      float4 f = *(const float4*)(vp + i * 4);
      tile[k][cq * 32 + i * 4]     = f.x;
      tile[k][cq * 32 + i * 4 + 1] = f.y;
      tile[k][cq * 32 + i * 4 + 2] = f.z;
      tile[k][cq * 32 + i * 4 + 3] = f.w;
    }
  }
  __syncthreads();

  // ---- V^T tile image (transposed + swizzled) ----
  {
    const int d = tid >> 1;
    const int h = tid & 1;
    unsigned short* vdst = Vt + (size_t)bid * 8192 + d * 64;
    const int xr = (d & 7) << 4;
#pragma unroll
    for (int jj = 0; jj < 4; ++jj) {
      const int k0 = h * 32 + jj * 8;
      uint4 u;
      u.x = bfpack2(tile[k0 + 0][d], tile[k0 + 1][d]);
      u.y = bfpack2(tile[k0 + 2][d], tile[k0 + 3][d]);
      u.z = bfpack2(tile[k0 + 4][d], tile[k0 + 5][d]);
      u.w = bfpack2(tile[k0 + 6][d], tile[k0 + 7][d]);
      const int o = (h * 64 + jj * 16) ^ xr;
      *(uint4*)(vdst + (o >> 1)) = u;
    }
  }
}

// ======================= worker kernel =======================
// R14 = R13 skeleton (4 waves, 128-q tile, atomic LPT, V single-buffer,
// P through dead K buffer, 49.2KB LDS) + two targeted changes:
//  (1) bf16 partial-O (halves split-K write traffic; one extra relative
//      rounding, normalized away by L in combine);
//  (2) parallel-subtile softmax: interleaved max-reduce chains, per-lane
//      DEFERRED l partial (cross-quad sum once at epilogue; alpha is
//      per-query-uniform so linearity holds), sub1 gets its own P-scratch
//      rows (rows 64..127 of the 16KB dead-K buffer) so the two P
//      roundtrips overlap. exp in-place over st -> no VGPR growth.

__global__ __launch_bounds__(256, 2)
void attn_worker(const float* __restrict__ Q, const unsigned short* __restrict__ Kb,
                 const unsigned short* __restrict__ Vt, int* __restrict__ cnt,
                 float* __restrict__ ml, unsigned short* __restrict__ pO) {
  __shared__ __align__(16) short Klds[2][8192];   // 2 x 16KB (also P scratch)
  __shared__ __align__(16) short Vtlds[8192];     // 16KB single buffer
  __shared__ int s_chunk;

  const int tid  = threadIdx.x;
  const int lane = tid & 63;
  const int w    = tid >> 6;        // wave 0..3
  const int l15  = lane & 15;
  const int quad = lane >> 4;
  const int xk   = (l15 & 7) << 3;  // short-index XOR for swizzled LDS reads

  const float CSC = 0.12752041f;    // log2(e)/sqrt(128)

  for (;;) {
    if (tid == 0) s_chunk = atomicAdd(cnt, 1);
    __syncthreads();
    const int c = s_chunk;
    if (c >= NCHUNK) break;

    // ---- decode: b = c&7; tiles enumerated q=31 down (LPT) ----
    const int b = c & 7;
    int q = 31, r = c >> 3;           // r in [0,144)
    while (r >= NC(q)) { r -= NC(q); --q; }
    const int j  = r;
    const int q0 = q * 128;
    const int s0 = j * CH;
    const int s1 = min(s0 + CH, 2 * q + 2);

    // ---- Q fragments for 2 subtiles (B-operand: n=l15=query, k=quad*8+i=d) ----
    short8 bq[2][4];
    int qg[2];
#pragma unroll
    for (int sub = 0; sub < 2; ++sub) {
      qg[sub] = q0 + w * 32 + sub * 16 + l15;
      const float* qrow = Q + (size_t)(b * S_LEN + qg[sub]) * D_K + quad * 8;
#pragma unroll
      for (int kd = 0; kd < 4; ++kd) {
        float4 f0 = *(const float4*)(qrow + kd * 32);
        float4 f1 = *(const float4*)(qrow + kd * 32 + 4);
        union { short8 s; unsigned u[4]; } tt;
        tt.u[0] = bfpack2(f0.x, f0.y);
        tt.u[1] = bfpack2(f0.z, f0.w);
        tt.u[2] = bfpack2(f1.x, f1.y);
        tt.u[3] = bfpack2(f1.z, f1.w);
        bq[sub][kd] = tt.s;
      }
    }

    floatx4 acc[2][8];
#pragma unroll
    for (int sub = 0; sub < 2; ++sub)
#pragma unroll
      for (int nc = 0; nc < 8; ++nc) acc[sub][nc] = (floatx4){0.f, 0.f, 0.f, 0.f};
    // l_run is a PER-LANE PARTIAL (this lane's quad-slice of the row sum);
    // cross-quad reduction deferred to the epilogue.
    float m_run[2] = {-1e30f, -1e30f}, l_run[2] = {0.f, 0.f};

    const unsigned short* kb0 = Kb + (size_t)b * 64 * 8192;   // tile images
    const unsigned short* vb0 = Vt + (size_t)b * 64 * 8192;
    const int lo = lane * 8;            // lane*16B in shorts

    // each wave stages its quarter (4KB) of a 16KB tile = 4 dma16
#define STAGE_K(BUF, S)                                                        \
    do {                                                                       \
      const unsigned short* kg_ = kb0 + (size_t)(S) * 8192 + w * 2048 + lo;    \
      short* kl_ = &Klds[BUF][w * 2048];                                       \
      _Pragma("unroll")                                                        \
      for (int i_ = 0; i_ < 4; ++i_) dma16(kg_ + i_ * 512, kl_ + i_ * 512);    \
    } while (0)
#define STAGE_V(S)                                                             \
    do {                                                                       \
      const unsigned short* vg_ = vb0 + (size_t)(S) * 8192 + w * 2048 + lo;    \
      short* vl_ = &Vtlds[w * 2048];                                           \
      _Pragma("unroll")                                                        \
      for (int i_ = 0; i_ < 4; ++i_) dma16(vg_ + i_ * 512, vl_ + i_ * 512);    \
    } while (0)

    // ---- prologue: K(s0), K(s0+1), V(s0); wait all, barrier ----
    STAGE_K(s0 & 1, s0);
    if (s0 + 1 < s1) STAGE_K((s0 + 1) & 1, s0 + 1);
    STAGE_V(s0);
    asm volatile("s_waitcnt vmcnt(0)" ::: "memory");
    __builtin_amdgcn_s_barrier();
    __builtin_amdgcn_sched_barrier(0);

    for (int s = s0; s < s1; ++s) {
      const int kt  = s * KB;
      const int cur = s & 1;
      const short* Kl = &Klds[cur][0];
      const bool act = (kt <= q0 + w * 32 + 31);   // wave fully masked beyond

      floatx4 st[2][4];
      if (act) {
        // ---- S^T = K*Q^T for both subtiles; each A-frag read used twice ----
        __builtin_amdgcn_s_setprio(1);
#pragma unroll
        for (int kf = 0; kf < 4; ++kf) {
          floatx4 c0 = (floatx4){0.f, 0.f, 0.f, 0.f};
          floatx4 c1 = (floatx4){0.f, 0.f, 0.f, 0.f};
#pragma unroll
          for (int kd = 0; kd < 4; ++kd) {
            short8 a = *(const short8*)(&Kl[((kf * 16 + l15) << 7) + ((kd * 32 + quad * 8) ^ xk)]);
            c0 = __builtin_amdgcn_mfma_f32_16x16x32_bf16(a, bq[0][kd], c0, 0, 0, 0);
            c1 = __builtin_amdgcn_mfma_f32_16x16x32_bf16(a, bq[1][kd], c1, 0, 0, 0);
          }
          st[0][kf] = c0;
          st[1][kf] = c1;
        }
        __builtin_amdgcn_s_setprio(0);

        // ---- causal mask (boundary subtiles only) ----
#pragma unroll
        for (int sub = 0; sub < 2; ++sub) {
          if (kt + 63 > q0 + w * 32 + sub * 16) {
#pragma unroll
            for (int kf = 0; kf < 4; ++kf)
#pragma unroll
              for (int rr = 0; rr < 4; ++rr) {
                int key = kt + kf * 16 + quad * 4 + rr;
                if (key > qg[sub]) st[sub][kf][rr] = -1e30f;
              }
          }
        }
      }

      // own DMAs (V(s), K(s+1)) done; barrier => ALL waves' DMAs visible AND
      // K[cur] fully consumed block-wide (becomes P scratch).
      asm volatile("s_waitcnt vmcnt(0)" ::: "memory");
      __builtin_amdgcn_s_barrier();
      __builtin_amdgcn_sched_barrier(0);

      short8 pa[2][2];
      if (act) {
        // ---- parallel-subtile online softmax ----
        float mx0 = st[0][0][0], mx1 = st[1][0][0];
#pragma unroll
        for (int kf = 0; kf < 4; ++kf)
#pragma unroll
          for (int rr = 0; rr < 4; ++rr) {
            mx0 = fmaxf(mx0, st[0][kf][rr]);
            mx1 = fmaxf(mx1, st[1][kf][rr]);
          }
        // interleaved cross-quad max (two independent shuffle chains)
        mx0 = fmaxf(mx0, __shfl_xor(mx0, 16, 64));
        mx1 = fmaxf(mx1, __shfl_xor(mx1, 16, 64));
        mx0 = fmaxf(mx0, __shfl_xor(mx0, 32, 64));
        mx1 = fmaxf(mx1, __shfl_xor(mx1, 32, 64));
        const float mn0 = fmaxf(m_run[0], mx0);
        const float mn1 = fmaxf(m_run[1], mx1);
        const bool  g0  = __any(mn0 > m_run[0]);
        const bool  g1  = __any(mn1 > m_run[1]);

        // exp in place (st becomes P); accumulate LOCAL partial sums
        float t0 = 0.f, t1 = 0.f;
#pragma unroll
        for (int kf = 0; kf < 4; ++kf)
#pragma unroll
          for (int rr = 0; rr < 4; ++rr) {
            st[0][kf][rr] = EXP2F((st[0][kf][rr] - mn0) * CSC); t0 += st[0][kf][rr];
            st[1][kf][rr] = EXP2F((st[1][kf][rr] - mn1) * CSC); t1 += st[1][kf][rr];
          }

        if (g0) {
          const float a0 = EXP2F((m_run[0] - mn0) * CSC);
          l_run[0] = l_run[0] * a0 + t0;
#pragma unroll
          for (int rr = 0; rr < 4; ++rr) {
            const float ar = __shfl(a0, quad * 4 + rr, 64);
#pragma unroll
            for (int nc = 0; nc < 8; ++nc) acc[0][nc][rr] *= ar;
          }
        } else l_run[0] += t0;
        if (g1) {
          const float a1 = EXP2F((m_run[1] - mn1) * CSC);
          l_run[1] = l_run[1] * a1 + t1;
#pragma unroll
          for (int rr = 0; rr < 4; ++rr) {
            const float ar = __shfl(a1, quad * 4 + rr, 64);
#pragma unroll
            for (int nc = 0; nc < 8; ++nc) acc[1][nc][rr] *= ar;
          }
        } else l_run[1] += t1;
        m_run[0] = mn0;
        m_run[1] = mn1;

        // P roundtrip: both subtiles to SEPARATE rows (sub1 at +8KB), one
        // fence, both reads -> the two LDS chains overlap.
        short* pw0 = &Klds[cur][(w * 16 + l15) << 6];
        short* pw1 = pw0 + 4096;
#pragma unroll
        for (int kf = 0; kf < 4; ++kf) {
          uint2 u0, u1;
          u0.x = cvtpk(st[0][kf][0], st[0][kf][1]);
          u0.y = cvtpk(st[0][kf][2], st[0][kf][3]);
          u1.x = cvtpk(st[1][kf][0], st[1][kf][1]);
          u1.y = cvtpk(st[1][kf][2], st[1][kf][3]);
          *(uint2*)(&pw0[(kf * 16 + quad * 4) ^ xk]) = u0;
          *(uint2*)(&pw1[(kf * 16 + quad * 4) ^ xk]) = u1;
        }
        __asm__ __volatile__("" ::: "memory");
        pa[0][0] = *(const short8*)(&pw0[(quad * 8) ^ xk]);
        pa[0][1] = *(const short8*)(&pw0[(32 + quad * 8) ^ xk]);
        pa[1][0] = *(const short8*)(&pw1[(quad * 8) ^ xk]);
        pa[1][1] = *(const short8*)(&pw1[(32 + quad * 8) ^ xk]);
        __asm__ __volatile__("" ::: "memory");

        // ---- O += P*V ; each B-frag read used by both subtiles ----
        __builtin_amdgcn_s_setprio(1);
#pragma unroll
        for (int nc = 0; nc < 8; ++nc) {
          short8 bv0 = *(const short8*)(&Vtlds[((nc * 16 + l15) << 6) + ((quad * 8) ^ xk)]);
          short8 bv1 = *(const short8*)(&Vtlds[((nc * 16 + l15) << 6) + ((32 + quad * 8) ^ xk)]);
          acc[0][nc] = __builtin_amdgcn_mfma_f32_16x16x32_bf16(pa[0][0], bv0, acc[0][nc], 0, 0, 0);
          acc[0][nc] = __builtin_amdgcn_mfma_f32_16x16x32_bf16(pa[0][1], bv1, acc[0][nc], 0, 0, 0);
          acc[1][nc] = __builtin_amdgcn_mfma_f32_16x16x32_bf16(pa[1][0], bv0, acc[1][nc], 0, 0, 0);
          acc[1][nc] = __builtin_amdgcn_mfma_f32_16x16x32_bf16(pa[1][1], bv1, acc[1][nc], 0, 0, 0);
        }
        __builtin_amdgcn_s_setprio(0);
      }

      // ---- all P-scratch & V reads done -> stage next ----
      asm volatile("s_waitcnt lgkmcnt(0)" ::: "memory");
      __builtin_amdgcn_s_barrier();
      __builtin_amdgcn_sched_barrier(0);
      if (s + 2 < s1) STAGE_K(cur, s + 2);
      if (s + 1 < s1) STAGE_V(s + 1);
      // no wait here: next step's vmcnt(0) (after QKT) covers these
    }
#undef STAGE_K
#undef STAGE_V

    // ---- partial epilogue: bf16 unnormalized O + (m, reduced l); slot == c ----
    unsigned short* po = pO + (size_t)c * 16384;
#pragma unroll
    for (int sub = 0; sub < 2; ++sub) {
      float lf = l_run[sub];                      // deferred cross-quad sum
      lf += __shfl_xor(lf, 16, 64);
      lf += __shfl_xor(lf, 32, 64);
#pragma unroll
      for (int rr = 0; rr < 4; ++rr) {
        const int qrow = w * 32 + sub * 16 + quad * 4 + rr;
        unsigned short* op = po + qrow * D_K + l15;
#pragma unroll
        for (int nc = 0; nc < 8; ++nc) op[nc * 16] = (unsigned short)bfround(acc[sub][nc][rr]);
      }
      if (quad == 0) {
        const int qrow = w * 32 + sub * 16 + l15;
        ml[(size_t)c * 256 + qrow * 2]     = m_run[sub];
        ml[(size_t)c * 256 + qrow * 2 + 1] = lf;
      }
    }
  }
}

// ======================= combine kernel =======================
// 256 blocks = b*32 + q (128-q tiles); up to 8 bf16 partials per tile.

__global__ __launch_bounds__(256)
void attn_combine(const float* __restrict__ ml, const unsigned short* __restrict__ pO,
                  float* __restrict__ O) {
  const int t = blockIdx.x;           // 0..255 = b*32 + q
  const int b = t >> 5;
  const int q = t & 31;
  const float CSC = 0.12752041f;

  const int tid = threadIdx.x;
  const int ql  = tid >> 1;           // 0..127
  const int dh  = (tid & 1) * 64;     // d-span of 64 floats

  int cum = 0;
  for (int tq = 31; tq > q; --tq) cum += NC(tq);
  const int ncb = NC(q);              // 1..8

  float m[8], l[8], wgt[8];
  float M = -1e30f;
#pragma unroll
  for (int i = 0; i < 8; ++i) {
    if (i < ncb) {
      const size_t slot = (size_t)((cum + i) << 3 | b);
      m[i] = ml[slot * 256 + ql * 2];
      l[i] = ml[slot * 256 + ql * 2 + 1];
      M = fmaxf(M, m[i]);
    }
  }
  float L = 0.f;
#pragma unroll
  for (int i = 0; i < 8; ++i)
    if (i < ncb) { wgt[i] = EXP2F((m[i] - M) * CSC); L += wgt[i] * l[i]; }
  const float inv = 1.0f / L;

  float out[64];
#pragma unroll
  for (int v = 0; v < 64; ++v) out[v] = 0.f;
#pragma unroll
  for (int i = 0; i < 8; ++i) {
    if (i < ncb) {
      const size_t slot = (size_t)((cum + i) << 3 | b);
      const unsigned short* src = pO + slot * 16384 + ql * D_K + dh;
      const float wj = wgt[i];
#pragma unroll
      for (int v = 0; v < 8; ++v) {
        short8 s8 = *(const short8*)(src + v * 8);
#pragma unroll
        for (int e = 0; e < 8; ++e)
          out[v * 8 + e] += wj * bf2f((unsigned short)s8[e]);
      }
    }
  }
  float* dst = O + ((size_t)(b * S_LEN) + q * 128 + ql) * D_K + dh;
#pragma unroll
  for (int v = 0; v < 16; ++v) {
    *(float4*)(dst + v * 4) = make_float4(out[v * 4] * inv, out[v * 4 + 1] * inv,
                                          out[v * 4 + 2] * inv, out[v * 4 + 3] * inv);
  }
}

// ======================= fallback (known-good, ws-too-small path) =======================

#define KT_STR 136
#define VT_STR 72
#define PT_STR 72

__global__ __launch_bounds__(256, 2)
void attn_fwd_fb(const float* __restrict__ Q, const float* __restrict__ K,
                 const float* __restrict__ V, float* __restrict__ O) {
  __shared__ __align__(16) short Klds[KB * KT_STR];
  __shared__ __align__(16) short Vtlds[D_K * VT_STR];
  __shared__ __align__(16) short Plds[4 * 16 * PT_STR];

  const int tid  = threadIdx.x;
  const int lane = tid & 63;
  const int w    = tid >> 6;
  const int l15  = lane & 15;
  const int quad = lane >> 4;

  const int bid = blockIdx.x;
  const int b   = bid & 7;
  const int qi  = 63 - (bid >> 3);
  const int q0  = qi * 64;

  const float CSC = 0.12752041f;

  const int    qg   = q0 + w * 16 + l15;
  const float* qrow = Q + (size_t)(b * S_LEN + qg) * D_K + quad * 8;
  short8 bq[4];
#pragma unroll
  for (int kd = 0; kd < 4; ++kd) {
    float4 f0 = *(const float4*)(qrow + kd * 32);
    float4 f1 = *(const float4*)(qrow + kd * 32 + 4);
    union { short8 s; unsigned u[4]; } t;
    t.u[0] = bfpack2(f0.x, f0.y);
    t.u[1] = bfpack2(f0.z, f0.w);
    t.u[2] = bfpack2(f1.x, f1.y);
    t.u[3] = bfpack2(f1.z, f1.w);
    bq[kd] = t.s;
  }

  floatx4 acc[8];
#pragma unroll
  for (int nc = 0; nc < 8; ++nc) acc[nc] = (floatx4){0.f, 0.f, 0.f, 0.f};
  float m_run = -1e30f, l_run = 0.f;

  const int d4 = tid & 31;
  const int kq = tid >> 5;
  const int nsteps = qi + 1;

  for (int s = 0; s < nsteps; ++s) {
    const int kt = s * KB;
#pragma unroll
    for (int r2 = 0; r2 < 2; ++r2) {
      const int row = r2 * 32 + kq * 4;
      const float* kp = K + (size_t)(b * S_LEN + kt + row) * D_K + d4 * 4;
      const float* vp = V + (size_t)(b * S_LEN + kt + row) * D_K + d4 * 4;
      float4 fk[4], fv[4];
#pragma unroll
      for (int i = 0; i < 4; ++i) {
        fk[i] = *(const float4*)(kp + i * D_K);
        fv[i] = *(const float4*)(vp + i * D_K);
      }
#pragma unroll
      for (int i = 0; i < 4; ++i) {
        uint2 u;
        u.x = bfpack2(fk[i].x, fk[i].y);
        u.y = bfpack2(fk[i].z, fk[i].w);
        *(uint2*)(&Klds[(row + i) * KT_STR + d4 * 4]) = u;
      }
#pragma unroll
      for (int c = 0; c < 4; ++c) {
        float e0 = ((const float*)&fv[0])[c];
        float e1 = ((const float*)&fv[1])[c];
        float e2 = ((const float*)&fv[2])[c];
        float e3 = ((const float*)&fv[3])[c];
        uint2 u;
        u.x = bfpack2(e0, e1);
        u.y = bfpack2(e2, e3);
        *(uint2*)(&Vtlds[(d4 * 4 + c) * VT_STR + row]) = u;
      }
    }
    __syncthreads();

    floatx4 st[4];
#pragma unroll
    for (int kf = 0; kf < 4; ++kf) {
      floatx4 cc = (floatx4){0.f, 0.f, 0.f, 0.f};
#pragma unroll
      for (int kd = 0; kd < 4; ++kd) {
        short8 a = *(const short8*)(&Klds[(kf * 16 + l15) * KT_STR + kd * 32 + quad * 8]);
        cc = __builtin_amdgcn_mfma_f32_16x16x32_bf16(a, bq[kd], cc, 0, 0, 0);
      }
      st[kf] = cc;
    }

    if (s == nsteps - 1) {
#pragma unroll
      for (int kf = 0; kf < 4; ++kf)
#pragma unroll
        for (int rr = 0; rr < 4; ++rr) {
          int key = kt + kf * 16 + quad * 4 + rr;
          if (key > qg) st[kf][rr] = -1e30f;
        }
    }

    float mx = st[0][0];
#pragma unroll
    for (int kf = 0; kf < 4; ++kf)
#pragma unroll
      for (int rr = 0; rr < 4; ++rr) mx = fmaxf(mx, st[kf][rr]);
    mx = fmaxf(mx, __shfl_xor(mx, 16, 64));
    mx = fmaxf(mx, __shfl_xor(mx, 32, 64));
    const float m_new = fmaxf(m_run, mx);
    const float alpha = EXP2F((m_run - m_new) * CSC);

    float p[4][4];
    float tsum = 0.f;
#pragma unroll
    for (int kf = 0; kf < 4; ++kf)
#pragma unroll
      for (int rr = 0; rr < 4; ++rr) {
        p[kf][rr] = EXP2F((st[kf][rr] - m_new) * CSC);
        tsum += p[kf][rr];
      }
    tsum += __shfl_xor(tsum, 16, 64);
    tsum += __shfl_xor(tsum, 32, 64);
    l_run = l_run * alpha + tsum;
    m_run = m_new;

#pragma unroll
    for (int rr = 0; rr < 4; ++rr) {
      const float ar = __shfl(alpha, quad * 4 + rr, 64);
#pragma unroll
      for (int nc = 0; nc < 8; ++nc) acc[nc][rr] *= ar;
    }

    short* pw = &Plds[(w * 16 + l15) * PT_STR];
#pragma unroll
    for (int kf = 0; kf < 4; ++kf) {
      uint2 u;
      u.x = bfpack2(p[kf][0], p[kf][1]);
      u.y = bfpack2(p[kf][2], p[kf][3]);
      *(uint2*)(&pw[kf * 16 + quad * 4]) = u;
    }
    __asm__ __volatile__("" ::: "memory");
    short8 pa0 = *(const short8*)(&pw[quad * 8]);
    short8 pa1 = *(const short8*)(&pw[32 + quad * 8]);

#pragma unroll
    for (int nc = 0; nc < 8; ++nc) {
      short8 bv0 = *(const short8*)(&Vtlds[(nc * 16 + l15) * VT_STR + quad * 8]);
      acc[nc] = __builtin_amdgcn_mfma_f32_16x16x32_bf16(pa0, bv0, acc[nc], 0, 0, 0);
      short8 bv1 = *(const short8*)(&Vtlds[(nc * 16 + l15) * VT_STR + 32 + quad * 8]);
      acc[nc] = __builtin_amdgcn_mfma_f32_16x16x32_bf16(pa1, bv1, acc[nc], 0, 0, 0);
    }
    __syncthreads();
  }

#pragma unroll
  for (int rr = 0; rr < 4; ++rr) {
    const float lr  = __shfl(l_run, quad * 4 + rr, 64);
    const float inv = 1.0f / lr;
    const int qout  = q0 + w * 16 + quad * 4 + rr;
    float* op = O + (size_t)(b * S_LEN + qout) * D_K + l15;
#pragma unroll
    for (int nc = 0; nc < 8; ++nc) op[nc * 16] = acc[nc][rr] * inv;
  }
}

// ======================= launch =======================

extern "C" void kernel_launch(void* const* d_in, const int* in_sizes, int n_in,
                              void* d_out, int out_size, void* d_ws, size_t ws_size,
                              hipStream_t stream) {
  const float* Q = (const float*)d_in[0];
  const float* K = (const float*)d_in[1];
  const float* V = (const float*)d_in[2];
  float* O = (float*)d_out;

  const size_t elems = (size_t)B_SZ * S_LEN * D_K;   // 4.19M

  // ws layout (bytes):
  //   0          : counter (int, 256B slot)
  //   256        : ml    [1152 slots][128 q][m,l] f32  =  1,179,648
  //   1,179,904  : partO [1152 slots][128 q][128 d] BF16 = 37,748,736
  //   38,928,640 : Kb tile-images bf16                 =  8,388,608
  //   47,317,248 : Vt tile-images bf16                 =  8,388,608
  //   need ~55.7 MB
  const size_t off_ml = 256;
  const size_t off_po = off_ml + (size_t)NCHUNK * 256 * 4;
  const size_t off_kb = off_po + (size_t)NCHUNK * 32768;
  const size_t off_vt = off_kb + elems * 2;
  const size_t need   = off_vt + elems * 2;

  if (ws_size >= need) {
    char* ws = (char*)d_ws;
    int*            cnt = (int*)ws;
    float*          mlp = (float*)(ws + off_ml);
    unsigned short* po  = (unsigned short*)(ws + off_po);
    unsigned short* Kbp = (unsigned short*)(ws + off_kb);
    unsigned short* Vtp = (unsigned short*)(ws + off_vt);

    prep<<<dim3(B_SZ * 64), dim3(256), 0, stream>>>(K, V, Kbp, Vtp, cnt);
    attn_worker<<<dim3(768), dim3(256), 0, stream>>>(Q, Kbp, Vtp, cnt, mlp, po);
    attn_combine<<<dim3(256), dim3(256), 0, stream>>>(mlp, po, O);
  } else {
    attn_fwd_fb<<<dim3(512), dim3(256), 0, stream>>>(Q, K, V, O);
  }
}

// Round 15
// 180.497 us; speedup vs baseline: 1.3220x; 1.0199x over previous
//
#include <hip/hip_runtime.h>

#define B_SZ   8
#define S_LEN  4096
#define D_K    128
#define KB     64      // keys per step
#define CH     16      // steps per chunk
// 128-q tiles (32/batch), tile q needs 2q+2 steps; chunks of <=16 steps:
// sum over q of ceil((2q+2)/16) = 80 per batch -> 640 chunks total.
#define NCHUNK 640
#define NC(q)  ((2*(q) + 17) >> 4)   // ceil((2q+2)/16) = chunks for tile q

typedef short  short8  __attribute__((ext_vector_type(8)));
typedef float  floatx4 __attribute__((ext_vector_type(4)));

// raw v_exp_f32 (2^x) where available; args are always <= 0 here
#if defined(__has_builtin)
#if __has_builtin(__builtin_amdgcn_exp2f)
#define EXP2F(x) __builtin_amdgcn_exp2f(x)
#endif
#endif
#ifndef EXP2F
#define EXP2F(x) exp2f(x)
#endif

__device__ __forceinline__ unsigned bfround(float x) {
  unsigned u = __builtin_bit_cast(unsigned, x);
  return (u + 0x7fffu + ((u >> 16) & 1u)) >> 16;
}
__device__ __forceinline__ unsigned bfpack2(float a, float b) {
  return bfround(a) | (bfround(b) << 16);
}
__device__ __forceinline__ float bf2f(unsigned short s) {
  return __builtin_bit_cast(float, ((unsigned)s) << 16);
}
// single-instruction RTNE pack (hot loop only; numerics validated R1-R14)
__device__ __forceinline__ unsigned cvtpk(float lo, float hi) {
  unsigned r;
  asm("v_cvt_pk_bf16_f32 %0, %1, %2" : "=v"(r) : "v"(lo), "v"(hi));
  return r;
}

// NOTE (R6): permlane16/32_swap reductions failed correctness. __shfl_xor only.
// NOTE (R9/R12): empirical __launch_bounds__ cap law on this toolchain:
// VGPR cap ~= 512/(2*arg). arg=2 -> 128 (fits ~112 working set); arg=3 -> 84
// (R1,R12: spill); arg=4@512thr -> 64 (R9: catastrophic). ALWAYS arg=2 here.

// Async global->LDS DMA, 16B per lane (wave writes 1024B contiguous LDS).
__device__ __forceinline__ void dma16(const void* g, const void* l) {
  __builtin_amdgcn_global_load_lds(
      (__attribute__((address_space(1))) unsigned int*)(unsigned long long)g,
      (__attribute__((address_space(3))) unsigned int*)(unsigned int)(unsigned long long)l,
      16, 0, 0);
}

// ======================= pre-pass: tile-image builder (R3-R14 proven) =======================
// One block per (b, step s): K and V^T as 16KB tile IMAGES with the XOR
// bank-swizzle baked in (byte ^= ((row&7)<<4)); worker DMAs them linearly.
// Block 0 zeroes the chunk counter.

__global__ __launch_bounds__(256)
void prep(const float* __restrict__ K, const float* __restrict__ V,
          unsigned short* __restrict__ Kb, unsigned short* __restrict__ Vt,
          int* __restrict__ cnt) {
  __shared__ float tile[64][129];
  const int tid = threadIdx.x;
  const int bid = blockIdx.x;         // b*64 + s
  if (bid == 0 && tid == 0) *cnt = 0;
  const int b   = bid >> 6;
  const int s   = bid & 63;
  const int kt  = s * 64;

  // ---- K tile image ----
  {
    const int r  = tid >> 2;
    const int cq = tid & 3;
    const float* kp = K + (size_t)(b * S_LEN + kt + r) * D_K + cq * 32;
    unsigned short* kdst = Kb + (size_t)bid * 8192 + r * 128;
    const int xr = (r & 7) << 4;
#pragma unroll
    for (int jj = 0; jj < 4; ++jj) {
      float4 f0 = *(const float4*)(kp + jj * 8);
      float4 f1 = *(const float4*)(kp + jj * 8 + 4);
      uint4 u;
      u.x = bfpack2(f0.x, f0.y);
      u.y = bfpack2(f0.z, f0.w);
      u.z = bfpack2(f1.x, f1.y);
      u.w = bfpack2(f1.z, f1.w);
      const int o = (cq * 64 + jj * 16) ^ xr;
      *(uint4*)(kdst + (o >> 1)) = u;
    }
  }

  // ---- V tile: load to LDS f32 ----
  {
    const int k  = tid >> 2;
    const int cq = tid & 3;
    const float* vp = V + (size_t)(b * S_LEN + kt + k) * D_K + cq * 32;
#pragma unroll
    for (int i = 0; i < 8; ++i) {
      float4 f = *(const float4*)(vp + i * 4);
      tile[k][cq * 32 + i * 4]     = f.x;
      tile[k][cq * 32 + i * 4 + 1] = f.y;
      tile[k][cq * 32 + i * 4 + 2] = f.z;
      tile[k][cq * 32 + i * 4 + 3] = f.w;
    }
  }
  __syncthreads();

  // ---- V^T tile image (transposed + swizzled) ----
  {
    const int d = tid >> 1;
    const int h = tid & 1;
    unsigned short* vdst = Vt + (size_t)bid * 8192 + d * 64;
    const int xr = (d & 7) << 4;
#pragma unroll
    for (int jj = 0; jj < 4; ++jj) {
      const int k0 = h * 32 + jj * 8;
      uint4 u;
      u.x = bfpack2(tile[k0 + 0][d], tile[k0 + 1][d]);
      u.y = bfpack2(tile[k0 + 2][d], tile[k0 + 3][d]);
      u.z = bfpack2(tile[k0 + 4][d], tile[k0 + 5][d]);
      u.w = bfpack2(tile[k0 + 6][d], tile[k0 + 7][d]);
      const int o = (h * 64 + jj * 16) ^ xr;
      *(uint4*)(vdst + (o >> 1)) = u;
    }
  }
}

// ======================= worker kernel =======================
// R15 = R14 worker with CH=16 split-K (640 chunks, one per residency slot:
// 3 blocks/CU x 256 CU >= 640 -> every chunk starts immediately, makespan =
// longest 16-step chain; halves Q-reload traffic, prologue drains, epilogues,
// and partial-O slots vs CH=8). Worker inner loop identical to R14:
// 4 waves, 128-q tile, atomic LPT, V single-buffer, P through dead K buffer,
// 49.2KB LDS, bf16 partial-O, parallel-subtile softmax with deferred l.

__global__ __launch_bounds__(256, 2)
void attn_worker(const float* __restrict__ Q, const unsigned short* __restrict__ Kb,
                 const unsigned short* __restrict__ Vt, int* __restrict__ cnt,
                 float* __restrict__ ml, unsigned short* __restrict__ pO) {
  __shared__ __align__(16) short Klds[2][8192];   // 2 x 16KB (also P scratch)
  __shared__ __align__(16) short Vtlds[8192];     // 16KB single buffer
  __shared__ int s_chunk;

  const int tid  = threadIdx.x;
  const int lane = tid & 63;
  const int w    = tid >> 6;        // wave 0..3
  const int l15  = lane & 15;
  const int quad = lane >> 4;
  const int xk   = (l15 & 7) << 3;  // short-index XOR for swizzled LDS reads

  const float CSC = 0.12752041f;    // log2(e)/sqrt(128)

  for (;;) {
    if (tid == 0) s_chunk = atomicAdd(cnt, 1);
    __syncthreads();
    const int c = s_chunk;
    if (c >= NCHUNK) break;

    // ---- decode: b = c&7; tiles enumerated q=31 down (LPT) ----
    const int b = c & 7;
    int q = 31, r = c >> 3;           // r in [0,80)
    while (r >= NC(q)) { r -= NC(q); --q; }
    const int j  = r;
    const int q0 = q * 128;
    const int s0 = j * CH;
    const int s1 = min(s0 + CH, 2 * q + 2);

    // ---- Q fragments for 2 subtiles (B-operand: n=l15=query, k=quad*8+i=d) ----
    short8 bq[2][4];
    int qg[2];
#pragma unroll
    for (int sub = 0; sub < 2; ++sub) {
      qg[sub] = q0 + w * 32 + sub * 16 + l15;
      const float* qrow = Q + (size_t)(b * S_LEN + qg[sub]) * D_K + quad * 8;
#pragma unroll
      for (int kd = 0; kd < 4; ++kd) {
        float4 f0 = *(const float4*)(qrow + kd * 32);
        float4 f1 = *(const float4*)(qrow + kd * 32 + 4);
        union { short8 s; unsigned u[4]; } tt;
        tt.u[0] = bfpack2(f0.x, f0.y);
        tt.u[1] = bfpack2(f0.z, f0.w);
        tt.u[2] = bfpack2(f1.x, f1.y);
        tt.u[3] = bfpack2(f1.z, f1.w);
        bq[sub][kd] = tt.s;
      }
    }

    floatx4 acc[2][8];
#pragma unroll
    for (int sub = 0; sub < 2; ++sub)
#pragma unroll
      for (int nc = 0; nc < 8; ++nc) acc[sub][nc] = (floatx4){0.f, 0.f, 0.f, 0.f};
    // l_run is a PER-LANE PARTIAL (this lane's quad-slice of the row sum);
    // cross-quad reduction deferred to the epilogue.
    float m_run[2] = {-1e30f, -1e30f}, l_run[2] = {0.f, 0.f};

    const unsigned short* kb0 = Kb + (size_t)b * 64 * 8192;   // tile images
    const unsigned short* vb0 = Vt + (size_t)b * 64 * 8192;
    const int lo = lane * 8;            // lane*16B in shorts

    // each wave stages its quarter (4KB) of a 16KB tile = 4 dma16
#define STAGE_K(BUF, S)                                                        \
    do {                                                                       \
      const unsigned short* kg_ = kb0 + (size_t)(S) * 8192 + w * 2048 + lo;    \
      short* kl_ = &Klds[BUF][w * 2048];                                       \
      _Pragma("unroll")                                                        \
      for (int i_ = 0; i_ < 4; ++i_) dma16(kg_ + i_ * 512, kl_ + i_ * 512);    \
    } while (0)
#define STAGE_V(S)                                                             \
    do {                                                                       \
      const unsigned short* vg_ = vb0 + (size_t)(S) * 8192 + w * 2048 + lo;    \
      short* vl_ = &Vtlds[w * 2048];                                           \
      _Pragma("unroll")                                                        \
      for (int i_ = 0; i_ < 4; ++i_) dma16(vg_ + i_ * 512, vl_ + i_ * 512);    \
    } while (0)

    // ---- prologue: K(s0), K(s0+1), V(s0); wait all, barrier ----
    STAGE_K(s0 & 1, s0);
    if (s0 + 1 < s1) STAGE_K((s0 + 1) & 1, s0 + 1);
    STAGE_V(s0);
    asm volatile("s_waitcnt vmcnt(0)" ::: "memory");
    __builtin_amdgcn_s_barrier();
    __builtin_amdgcn_sched_barrier(0);

    for (int s = s0; s < s1; ++s) {
      const int kt  = s * KB;
      const int cur = s & 1;
      const short* Kl = &Klds[cur][0];
      const bool act = (kt <= q0 + w * 32 + 31);   // wave fully masked beyond

      floatx4 st[2][4];
      if (act) {
        // ---- S^T = K*Q^T for both subtiles; each A-frag read used twice ----
        __builtin_amdgcn_s_setprio(1);
#pragma unroll
        for (int kf = 0; kf < 4; ++kf) {
          floatx4 c0 = (floatx4){0.f, 0.f, 0.f, 0.f};
          floatx4 c1 = (floatx4){0.f, 0.f, 0.f, 0.f};
#pragma unroll
          for (int kd = 0; kd < 4; ++kd) {
            short8 a = *(const short8*)(&Kl[((kf * 16 + l15) << 7) + ((kd * 32 + quad * 8) ^ xk)]);
            c0 = __builtin_amdgcn_mfma_f32_16x16x32_bf16(a, bq[0][kd], c0, 0, 0, 0);
            c1 = __builtin_amdgcn_mfma_f32_16x16x32_bf16(a, bq[1][kd], c1, 0, 0, 0);
          }
          st[0][kf] = c0;
          st[1][kf] = c1;
        }
        __builtin_amdgcn_s_setprio(0);

        // ---- causal mask (boundary subtiles only) ----
#pragma unroll
        for (int sub = 0; sub < 2; ++sub) {
          if (kt + 63 > q0 + w * 32 + sub * 16) {
#pragma unroll
            for (int kf = 0; kf < 4; ++kf)
#pragma unroll
              for (int rr = 0; rr < 4; ++rr) {
                int key = kt + kf * 16 + quad * 4 + rr;
                if (key > qg[sub]) st[sub][kf][rr] = -1e30f;
              }
          }
        }
      }

      // own DMAs (V(s), K(s+1)) done; barrier => ALL waves' DMAs visible AND
      // K[cur] fully consumed block-wide (becomes P scratch).
      asm volatile("s_waitcnt vmcnt(0)" ::: "memory");
      __builtin_amdgcn_s_barrier();
      __builtin_amdgcn_sched_barrier(0);

      short8 pa[2][2];
      if (act) {
        // ---- parallel-subtile online softmax ----
        float mx0 = st[0][0][0], mx1 = st[1][0][0];
#pragma unroll
        for (int kf = 0; kf < 4; ++kf)
#pragma unroll
          for (int rr = 0; rr < 4; ++rr) {
            mx0 = fmaxf(mx0, st[0][kf][rr]);
            mx1 = fmaxf(mx1, st[1][kf][rr]);
          }
        // interleaved cross-quad max (two independent shuffle chains)
        mx0 = fmaxf(mx0, __shfl_xor(mx0, 16, 64));
        mx1 = fmaxf(mx1, __shfl_xor(mx1, 16, 64));
        mx0 = fmaxf(mx0, __shfl_xor(mx0, 32, 64));
        mx1 = fmaxf(mx1, __shfl_xor(mx1, 32, 64));
        const float mn0 = fmaxf(m_run[0], mx0);
        const float mn1 = fmaxf(m_run[1], mx1);
        const bool  g0  = __any(mn0 > m_run[0]);
        const bool  g1  = __any(mn1 > m_run[1]);

        // exp in place (st becomes P); accumulate LOCAL partial sums
        float t0 = 0.f, t1 = 0.f;
#pragma unroll
        for (int kf = 0; kf < 4; ++kf)
#pragma unroll
          for (int rr = 0; rr < 4; ++rr) {
            st[0][kf][rr] = EXP2F((st[0][kf][rr] - mn0) * CSC); t0 += st[0][kf][rr];
            st[1][kf][rr] = EXP2F((st[1][kf][rr] - mn1) * CSC); t1 += st[1][kf][rr];
          }

        if (g0) {
          const float a0 = EXP2F((m_run[0] - mn0) * CSC);
          l_run[0] = l_run[0] * a0 + t0;
#pragma unroll
          for (int rr = 0; rr < 4; ++rr) {
            const float ar = __shfl(a0, quad * 4 + rr, 64);
#pragma unroll
            for (int nc = 0; nc < 8; ++nc) acc[0][nc][rr] *= ar;
          }
        } else l_run[0] += t0;
        if (g1) {
          const float a1 = EXP2F((m_run[1] - mn1) * CSC);
          l_run[1] = l_run[1] * a1 + t1;
#pragma unroll
          for (int rr = 0; rr < 4; ++rr) {
            const float ar = __shfl(a1, quad * 4 + rr, 64);
#pragma unroll
            for (int nc = 0; nc < 8; ++nc) acc[1][nc][rr] *= ar;
          }
        } else l_run[1] += t1;
        m_run[0] = mn0;
        m_run[1] = mn1;

        // P roundtrip: both subtiles to SEPARATE rows (sub1 at +8KB), one
        // fence, both reads -> the two LDS chains overlap.
        short* pw0 = &Klds[cur][(w * 16 + l15) << 6];
        short* pw1 = pw0 + 4096;
#pragma unroll
        for (int kf = 0; kf < 4; ++kf) {
          uint2 u0, u1;
          u0.x = cvtpk(st[0][kf][0], st[0][kf][1]);
          u0.y = cvtpk(st[0][kf][2], st[0][kf][3]);
          u1.x = cvtpk(st[1][kf][0], st[1][kf][1]);
          u1.y = cvtpk(st[1][kf][2], st[1][kf][3]);
          *(uint2*)(&pw0[(kf * 16 + quad * 4) ^ xk]) = u0;
          *(uint2*)(&pw1[(kf * 16 + quad * 4) ^ xk]) = u1;
        }
        __asm__ __volatile__("" ::: "memory");
        pa[0][0] = *(const short8*)(&pw0[(quad * 8) ^ xk]);
        pa[0][1] = *(const short8*)(&pw0[(32 + quad * 8) ^ xk]);
        pa[1][0] = *(const short8*)(&pw1[(quad * 8) ^ xk]);
        pa[1][1] = *(const short8*)(&pw1[(32 + quad * 8) ^ xk]);
        __asm__ __volatile__("" ::: "memory");

        // ---- O += P*V ; each B-frag read used by both subtiles ----
        __builtin_amdgcn_s_setprio(1);
#pragma unroll
        for (int nc = 0; nc < 8; ++nc) {
          short8 bv0 = *(const short8*)(&Vtlds[((nc * 16 + l15) << 6) + ((quad * 8) ^ xk)]);
          short8 bv1 = *(const short8*)(&Vtlds[((nc * 16 + l15) << 6) + ((32 + quad * 8) ^ xk)]);
          acc[0][nc] = __builtin_amdgcn_mfma_f32_16x16x32_bf16(pa[0][0], bv0, acc[0][nc], 0, 0, 0);
          acc[0][nc] = __builtin_amdgcn_mfma_f32_16x16x32_bf16(pa[0][1], bv1, acc[0][nc], 0, 0, 0);
          acc[1][nc] = __builtin_amdgcn_mfma_f32_16x16x32_bf16(pa[1][0], bv0, acc[1][nc], 0, 0, 0);
          acc[1][nc] = __builtin_amdgcn_mfma_f32_16x16x32_bf16(pa[1][1], bv1, acc[1][nc], 0, 0, 0);
        }
        __builtin_amdgcn_s_setprio(0);
      }

      // ---- all P-scratch & V reads done -> stage next ----
      asm volatile("s_waitcnt lgkmcnt(0)" ::: "memory");
      __builtin_amdgcn_s_barrier();
      __builtin_amdgcn_sched_barrier(0);
      if (s + 2 < s1) STAGE_K(cur, s + 2);
      if (s + 1 < s1) STAGE_V(s + 1);
      // no wait here: next step's vmcnt(0) (after QKT) covers these
    }
#undef STAGE_K
#undef STAGE_V

    // ---- partial epilogue: bf16 unnormalized O + (m, reduced l); slot == c ----
    unsigned short* po = pO + (size_t)c * 16384;
#pragma unroll
    for (int sub = 0; sub < 2; ++sub) {
      float lf = l_run[sub];                      // deferred cross-quad sum
      lf += __shfl_xor(lf, 16, 64);
      lf += __shfl_xor(lf, 32, 64);
#pragma unroll
      for (int rr = 0; rr < 4; ++rr) {
        const int qrow = w * 32 + sub * 16 + quad * 4 + rr;
        unsigned short* op = po + qrow * D_K + l15;
#pragma unroll
        for (int nc = 0; nc < 8; ++nc) op[nc * 16] = (unsigned short)bfround(acc[sub][nc][rr]);
      }
      if (quad == 0) {
        const int qrow = w * 32 + sub * 16 + l15;
        ml[(size_t)c * 256 + qrow * 2]     = m_run[sub];
        ml[(size_t)c * 256 + qrow * 2 + 1] = lf;
      }
    }
  }
}

// ======================= combine kernel =======================
// 256 blocks = b*32 + q (128-q tiles); up to 4 bf16 partials per tile.

__global__ __launch_bounds__(256)
void attn_combine(const float* __restrict__ ml, const unsigned short* __restrict__ pO,
                  float* __restrict__ O) {
  const int t = blockIdx.x;           // 0..255 = b*32 + q
  const int b = t >> 5;
  const int q = t & 31;
  const float CSC = 0.12752041f;

  const int tid = threadIdx.x;
  const int ql  = tid >> 1;           // 0..127
  const int dh  = (tid & 1) * 64;     // d-span of 64 floats

  int cum = 0;
  for (int tq = 31; tq > q; --tq) cum += NC(tq);
  const int ncb = NC(q);              // 1..4

  float m[4], l[4], wgt[4];
  float M = -1e30f;
#pragma unroll
  for (int i = 0; i < 4; ++i) {
    if (i < ncb) {
      const size_t slot = (size_t)((cum + i) << 3 | b);
      m[i] = ml[slot * 256 + ql * 2];
      l[i] = ml[slot * 256 + ql * 2 + 1];
      M = fmaxf(M, m[i]);
    }
  }
  float L = 0.f;
#pragma unroll
  for (int i = 0; i < 4; ++i)
    if (i < ncb) { wgt[i] = EXP2F((m[i] - M) * CSC); L += wgt[i] * l[i]; }
  const float inv = 1.0f / L;

  float out[64];
#pragma unroll
  for (int v = 0; v < 64; ++v) out[v] = 0.f;
#pragma unroll
  for (int i = 0; i < 4; ++i) {
    if (i < ncb) {
      const size_t slot = (size_t)((cum + i) << 3 | b);
      const unsigned short* src = pO + slot * 16384 + ql * D_K + dh;
      const float wj = wgt[i];
#pragma unroll
      for (int v = 0; v < 8; ++v) {
        short8 s8 = *(const short8*)(src + v * 8);
#pragma unroll
        for (int e = 0; e < 8; ++e)
          out[v * 8 + e] += wj * bf2f((unsigned short)s8[e]);
      }
    }
  }
  float* dst = O + ((size_t)(b * S_LEN) + q * 128 + ql) * D_K + dh;
#pragma unroll
  for (int v = 0; v < 16; ++v) {
    *(float4*)(dst + v * 4) = make_float4(out[v * 4] * inv, out[v * 4 + 1] * inv,
                                          out[v * 4 + 2] * inv, out[v * 4 + 3] * inv);
  }
}

// ======================= fallback (known-good, ws-too-small path) =======================

#define KT_STR 136
#define VT_STR 72
#define PT_STR 72

__global__ __launch_bounds__(256, 2)
void attn_fwd_fb(const float* __restrict__ Q, const float* __restrict__ K,
                 const float* __restrict__ V, float* __restrict__ O) {
  __shared__ __align__(16) short Klds[KB * KT_STR];
  __shared__ __align__(16) short Vtlds[D_K * VT_STR];
  __shared__ __align__(16) short Plds[4 * 16 * PT_STR];

  const int tid  = threadIdx.x;
  const int lane = tid & 63;
  const int w    = tid >> 6;
  const int l15  = lane & 15;
  const int quad = lane >> 4;

  const int bid = blockIdx.x;
  const int b   = bid & 7;
  const int qi  = 63 - (bid >> 3);
  const int q0  = qi * 64;

  const float CSC = 0.12752041f;

  const int    qg   = q0 + w * 16 + l15;
  const float* qrow = Q + (size_t)(b * S_LEN + qg) * D_K + quad * 8;
  short8 bq[4];
#pragma unroll
  for (int kd = 0; kd < 4; ++kd) {
    float4 f0 = *(const float4*)(qrow + kd * 32);
    float4 f1 = *(const float4*)(qrow + kd * 32 + 4);
    union { short8 s; unsigned u[4]; } t;
    t.u[0] = bfpack2(f0.x, f0.y);
    t.u[1] = bfpack2(f0.z, f0.w);
    t.u[2] = bfpack2(f1.x, f1.y);
    t.u[3] = bfpack2(f1.z, f1.w);
    bq[kd] = t.s;
  }

  floatx4 acc[8];
#pragma unroll
  for (int nc = 0; nc < 8; ++nc) acc[nc] = (floatx4){0.f, 0.f, 0.f, 0.f};
  float m_run = -1e30f, l_run = 0.f;

  const int d4 = tid & 31;
  const int kq = tid >> 5;
  const int nsteps = qi + 1;

  for (int s = 0; s < nsteps; ++s) {
    const int kt = s * KB;
#pragma unroll
    for (int r2 = 0; r2 < 2; ++r2) {
      const int row = r2 * 32 + kq * 4;
      const float* kp = K + (size_t)(b * S_LEN + kt + row) * D_K + d4 * 4;
      const float* vp = V + (size_t)(b * S_LEN + kt + row) * D_K + d4 * 4;
      float4 fk[4], fv[4];
#pragma unroll
      for (int i = 0; i < 4; ++i) {
        fk[i] = *(const float4*)(kp + i * D_K);
        fv[i] = *(const float4*)(vp + i * D_K);
      }
#pragma unroll
      for (int i = 0; i < 4; ++i) {
        uint2 u;
        u.x = bfpack2(fk[i].x, fk[i].y);
        u.y = bfpack2(fk[i].z, fk[i].w);
        *(uint2*)(&Klds[(row + i) * KT_STR + d4 * 4]) = u;
      }
#pragma unroll
      for (int c = 0; c < 4; ++c) {
        float e0 = ((const float*)&fv[0])[c];
        float e1 = ((const float*)&fv[1])[c];
        float e2 = ((const float*)&fv[2])[c];
        float e3 = ((const float*)&fv[3])[c];
        uint2 u;
        u.x = bfpack2(e0, e1);
        u.y = bfpack2(e2, e3);
        *(uint2*)(&Vtlds[(d4 * 4 + c) * VT_STR + row]) = u;
      }
    }
    __syncthreads();

    floatx4 st[4];
#pragma unroll
    for (int kf = 0; kf < 4; ++kf) {
      floatx4 cc = (floatx4){0.f, 0.f, 0.f, 0.f};
#pragma unroll
      for (int kd = 0; kd < 4; ++kd) {
        short8 a = *(const short8*)(&Klds[(kf * 16 + l15) * KT_STR + kd * 32 + quad * 8]);
        cc = __builtin_amdgcn_mfma_f32_16x16x32_bf16(a, bq[kd], cc, 0, 0, 0);
      }
      st[kf] = cc;
    }

    if (s == nsteps - 1) {
#pragma unroll
      for (int kf = 0; kf < 4; ++kf)
#pragma unroll
        for (int rr = 0; rr < 4; ++rr) {
          int key = kt + kf * 16 + quad * 4 + rr;
          if (key > qg) st[kf][rr] = -1e30f;
        }
    }

    float mx = st[0][0];
#pragma unroll
    for (int kf = 0; kf < 4; ++kf)
#pragma unroll
      for (int rr = 0; rr < 4; ++rr) mx = fmaxf(mx, st[kf][rr]);
    mx = fmaxf(mx, __shfl_xor(mx, 16, 64));
    mx = fmaxf(mx, __shfl_xor(mx, 32, 64));
    const float m_new = fmaxf(m_run, mx);
    const float alpha = EXP2F((m_run - m_new) * CSC);

    float p[4][4];
    float tsum = 0.f;
#pragma unroll
    for (int kf = 0; kf < 4; ++kf)
#pragma unroll
      for (int rr = 0; rr < 4; ++rr) {
        p[kf][rr] = EXP2F((st[kf][rr] - m_new) * CSC);
        tsum += p[kf][rr];
      }
    tsum += __shfl_xor(tsum, 16, 64);
    tsum += __shfl_xor(tsum, 32, 64);
    l_run = l_run * alpha + tsum;
    m_run = m_new;

#pragma unroll
    for (int rr = 0; rr < 4; ++rr) {
      const float ar = __shfl(alpha, quad * 4 + rr, 64);
#pragma unroll
      for (int nc = 0; nc < 8; ++nc) acc[nc][rr] *= ar;
    }

    short* pw = &Plds[(w * 16 + l15) * PT_STR];
#pragma unroll
    for (int kf = 0; kf < 4; ++kf) {
      uint2 u;
      u.x = bfpack2(p[kf][0], p[kf][1]);
      u.y = bfpack2(p[kf][2], p[kf][3]);
      *(uint2*)(&pw[kf * 16 + quad * 4]) = u;
    }
    __asm__ __volatile__("" ::: "memory");
    short8 pa0 = *(const short8*)(&pw[quad * 8]);
    short8 pa1 = *(const short8*)(&pw[32 + quad * 8]);

#pragma unroll
    for (int nc = 0; nc < 8; ++nc) {
      short8 bv0 = *(const short8*)(&Vtlds[(nc * 16 + l15) * VT_STR + quad * 8]);
      acc[nc] = __builtin_amdgcn_mfma_f32_16x16x32_bf16(pa0, bv0, acc[nc], 0, 0, 0);
      short8 bv1 = *(const short8*)(&Vtlds[(nc * 16 + l15) * VT_STR + 32 + quad * 8]);
      acc[nc] = __builtin_amdgcn_mfma_f32_16x16x32_bf16(pa1, bv1, acc[nc], 0, 0, 0);
    }
    __syncthreads();
  }

#pragma unroll
  for (int rr = 0; rr < 4; ++rr) {
    const float lr  = __shfl(l_run, quad * 4 + rr, 64);
    const float inv = 1.0f / lr;
    const int qout  = q0 + w * 16 + quad * 4 + rr;
    float* op = O + (size_t)(b * S_LEN + qout) * D_K + l15;
#pragma unroll
    for (int nc = 0; nc < 8; ++nc) op[nc * 16] = acc[nc][rr] * inv;
  }
}

// ======================= launch =======================

extern "C" void kernel_launch(void* const* d_in, const int* in_sizes, int n_in,
                              void* d_out, int out_size, void* d_ws, size_t ws_size,
                              hipStream_t stream) {
  const float* Q = (const float*)d_in[0];
  const float* K = (const float*)d_in[1];
  const float* V = (const float*)d_in[2];
  float* O = (float*)d_out;

  const size_t elems = (size_t)B_SZ * S_LEN * D_K;   // 4.19M

  // ws layout (bytes):
  //   0          : counter (int, 256B slot)
  //   256        : ml    [640 slots][128 q][m,l] f32    =    655,360
  //   655,616    : partO [640 slots][128 q][128 d] BF16 = 20,971,520
  //   21,627,136 : Kb tile-images bf16                  =  8,388,608
  //   30,015,744 : Vt tile-images bf16                  =  8,388,608
  //   need ~38.4 MB
  const size_t off_ml = 256;
  const size_t off_po = off_ml + (size_t)NCHUNK * 256 * 4;
  const size_t off_kb = off_po + (size_t)NCHUNK * 32768;
  const size_t off_vt = off_kb + elems * 2;
  const size_t need   = off_vt + elems * 2;

  if (ws_size >= need) {
    char* ws = (char*)d_ws;
    int*            cnt = (int*)ws;
    float*          mlp = (float*)(ws + off_ml);
    unsigned short* po  = (unsigned short*)(ws + off_po);
    unsigned short* Kbp = (unsigned short*)(ws + off_kb);
    unsigned short* Vtp = (unsigned short*)(ws + off_vt);

    prep<<<dim3(B_SZ * 64), dim3(256), 0, stream>>>(K, V, Kbp, Vtp, cnt);
    attn_worker<<<dim3(NCHUNK), dim3(256), 0, stream>>>(Q, Kbp, Vtp, cnt, mlp, po);
    attn_combine<<<dim3(256), dim3(256), 0, stream>>>(mlp, po, O);
  } else {
    attn_fwd_fb<<<dim3(512), dim3(256), 0, stream>>>(Q, K, V, O);
  }
}